// Round 4
// baseline (875.449 us; speedup 1.0000x reference)
//
#include <hip/hip_runtime.h>
#include <hip/hip_bf16.h>
#include <math.h>

// ---- problem constants ----
#define S_    2048
#define NC_   7
#define MAXK  819
#define NK    1024          // padded top-k rows (4*256)
#define Z_    14            // B*NUM_CATS
#define NEGV  (-10000.0f)

typedef __attribute__((ext_vector_type(8))) short bf16x8;
typedef __attribute__((ext_vector_type(4))) float f32x4;

#define CFENCE asm volatile("" ::: "memory")
#define BAR    do { CFENCE; __builtin_amdgcn_s_barrier(); CFENCE; } while (0)

__device__ __forceinline__ void gload_lds16(const void* g, void* l) {
  __builtin_amdgcn_global_load_lds((const __attribute__((address_space(1))) unsigned int*)g,
                                   (__attribute__((address_space(3))) unsigned int*)l, 16, 0, 0);
}

__device__ __forceinline__ float gelu_exact(float x) {
  return 0.5f * x * (1.0f + erff(x * 0.70710678118654752f));
}
__device__ __forceinline__ unsigned short f2bf(float x) {
  __hip_bfloat16 h = __float2bfloat16(x);
  return *(unsigned short*)&h;
}
__device__ __forceinline__ float bf2f(unsigned short u) {
  __hip_bfloat16 h; *(unsigned short*)&h = u;
  return __bfloat162float(h);
}

// ============ 256x256 8-wave GEMM, BK=64, deep-prefetch counted pipeline ============
// C[m,n] = sum_k A[m,k]*B[n,k]  (both row-major with K inner)
// EPI 0: optional bias1[n]; EPI 1: bias1/bias2 split at n=1024; EPI 2: logits epilogue
template<bool OBF16, int EPI>
__global__ __launch_bounds__(512, 2) void k_gemm8(
    const __hip_bfloat16* __restrict__ A, const __hip_bfloat16* __restrict__ B,
    void* __restrict__ Cv, const float* __restrict__ bias1, const float* __restrict__ bias2,
    const float* __restrict__ tkv, const int* __restrict__ kvp,
    int K, int nbn, long strideA, long strideB, int bmod7, long strideC,
    int ldc, int Mstore, int Nstore)
{
  __shared__ __align__(16) char lds[2][65536];   // per buf: A[0,32K) B[32K,64K)
  const int tid = threadIdx.x;
  const int z = blockIdx.z;
  const int nwg = gridDim.x;
  const int xcd = blockIdx.x & 7, loc = blockIdx.x >> 3;
  const int q = nwg >> 3, r = nwg & 7;
  const int wg = (xcd < r ? xcd * (q + 1) : r * (q + 1) + (xcd - r) * q) + loc;
  const int bm = wg / nbn, bn = wg % nbn;
  const int m0 = bm * 256, n0 = bn * 256;
  const __hip_bfloat16* pA = A + (long)z * strideA;
  const __hip_bfloat16* pB = B + (long)(bmod7 ? (z % 7) : z) * strideB;
  const int wave = tid >> 6, lane = tid & 63;
  const int wm = wave >> 2, wn = wave & 3;
  const int lr = lane & 15, kh = lane >> 4;
  const long Kb = (long)K * 2;

  f32x4 acc[8][4];
  #pragma unroll
  for (int i = 0; i < 8; ++i)
    #pragma unroll
    for (int j = 0; j < 4; ++j)
      #pragma unroll
      for (int rr = 0; rr < 4; ++rr) acc[i][j][rr] = 0.0f;

  // stage one 16KB half-tile (rows rh*128..+127 of A or B) of K-tile kt into buf bb
  auto stageHalf = [&](int bb, int isB, int rh, int kt) {
    const __hip_bfloat16* src = isB ? pB : pA;
    const int base0 = isB ? n0 : m0;
    const long kbyte = (long)kt * 128;
    #pragma unroll
    for (int j = 0; j < 2; ++j) {
      int off = j * 8192 + tid * 16;
      int row = rh * 128 + (off >> 7);
      int col = off & 127;
      int gc = col ^ ((row & 7) << 4);          // inverse swizzle on global source
      gload_lds16((const char*)src + (long)(base0 + row) * Kb + kbyte + gc,
                  &lds[bb][isB * 32768 + row * 128 + col]);
    }
  };
  auto stageAll = [&](int bb, int kt) {
    stageHalf(bb, 1, 0, kt);
    stageHalf(bb, 1, 1, kt);
    stageHalf(bb, 0, 0, kt);
    stageHalf(bb, 0, 1, kt);
  };
  auto readA = [&](int c, int g, int kk) -> bf16x8 {
    int row = wm * 128 + g * 16 + lr;
    int colb = kk * 64 + kh * 16;
    return *(const bf16x8*)&lds[c][row * 128 + (colb ^ ((row & 7) << 4))];
  };
  auto readB = [&](int c, int ni, int kk) -> bf16x8 {
    int row = wn * 64 + ni * 16 + lr;
    int colb = kk * 64 + kh * 16;
    return *(const bf16x8*)&lds[c][32768 + row * 128 + (colb ^ ((row & 7) << 4))];
  };
  auto mfma4 = [&](int g0, bf16x8* af, bf16x8* bfr) {
    __builtin_amdgcn_s_setprio(1);
    #pragma unroll
    for (int mi = 0; mi < 4; ++mi)
      #pragma unroll
      for (int ni = 0; ni < 4; ++ni)
        acc[g0 + mi][ni] = __builtin_amdgcn_mfma_f32_16x16x32_bf16(af[mi], bfr[ni], acc[g0 + mi][ni], 0, 0, 0);
    __builtin_amdgcn_s_setprio(0);
  };

  const int nt = K >> 6;
  // prologue: stage all of tile 0
  stageAll(0, 0);
  asm volatile("s_waitcnt vmcnt(0)" ::: "memory");
  BAR;

  bf16x8 bfr[4], a0f[4], a1f[4];
  for (int t = 0; t < nt; ++t) {
    const int c = t & 1, cn = c ^ 1;
    // ---- phase 0: B kk0 + A g0-3 kk0 ; stage ALL of tile t+1 (deep prefetch) ----
    #pragma unroll
    for (int i = 0; i < 4; ++i) bfr[i] = readB(c, i, 0);
    #pragma unroll
    for (int i = 0; i < 4; ++i) a0f[i] = readA(c, i, 0);
    if (t + 1 < nt) stageAll(cn, t + 1);
    BAR;
    mfma4(0, a0f, bfr);
    BAR;
    // ---- phase 1: A g4-7 kk0 ----
    #pragma unroll
    for (int i = 0; i < 4; ++i) a1f[i] = readA(c, 4 + i, 0);
    BAR;
    mfma4(4, a1f, bfr);
    BAR;
    // ---- phase 2: B kk1 + A g0-3 kk1 ----
    #pragma unroll
    for (int i = 0; i < 4; ++i) bfr[i] = readB(c, i, 1);
    #pragma unroll
    for (int i = 0; i < 4; ++i) a0f[i] = readA(c, i, 1);
    BAR;
    mfma4(0, a0f, bfr);
    BAR;
    // ---- phase 3: A g4-7 kk1 ; wait for t+1's loads (issued ~7 phases ago) ----
    #pragma unroll
    for (int i = 0; i < 4; ++i) a1f[i] = readA(c, 4 + i, 1);
    asm volatile("s_waitcnt vmcnt(0)" ::: "memory");
    BAR;
    mfma4(4, a1f, bfr);
    BAR;
  }

  const long coff = (long)z * strideC;
  int kval = 0, bb_ = 0;
  if (EPI == 2) { bb_ = z / NC_; kval = kvp[bb_]; }
  #pragma unroll
  for (int mi = 0; mi < 8; ++mi) {
    #pragma unroll
    for (int ni = 0; ni < 4; ++ni) {
      int n = n0 + wn * 64 + ni * 16 + lr;
      if (n >= Nstore) continue;
      float badd = 0.f;
      if (EPI == 0) { if (bias1) badd = bias1[n]; }
      if (EPI == 1) badd = (n >= 1024) ? bias2[n - 1024] : bias1[n];
      if (EPI == 2) badd = bias1[z * NK + n] + tkv[bb_ * NK + n];
      #pragma unroll
      for (int rr = 0; rr < 4; ++rr) {
        int m = m0 + wm * 128 + mi * 16 + kh * 4 + rr;
        if (m >= Mstore) continue;
        float v = acc[mi][ni][rr] + badd;
        if (EPI == 2) {
          v += tkv[bb_ * NK + m];
          if (!(n < m && n < kval)) v += NEGV;
        }
        if (OBF16) ((__hip_bfloat16*)Cv)[coff + (long)m * ldc + n] = __float2bfloat16(v);
        else       ((float*)Cv)[coff + (long)m * ldc + n] = v;
      }
    }
  }
}

// ---------- pack split3: dst rows 3072 wide. APAT: [hi|hi|lo]; else [hi|lo|hi] ----------
template<bool APAT>
__global__ __launch_bounds__(256) void k_packsplit3(const float* __restrict__ s1, long stride1,
                                                    const float* __restrict__ s2, int split,
                                                    __hip_bfloat16* __restrict__ dst) {
  long idx4 = ((long)blockIdx.x * 256 + threadIdx.x) * 4;
  int rrow = (int)(idx4 >> 10), c = (int)(idx4 & 1023);
  const float* src = (rrow < split) ? s1 + (long)rrow * stride1 + c
                                    : s2 + (long)(rrow - split) * 1024 + c;
  float4 v = *(const float4*)src;
  float f[4] = {v.x, v.y, v.z, v.w};
  unsigned short h[4], l4[4];
  #pragma unroll
  for (int i = 0; i < 4; ++i) {
    h[i] = f2bf(f[i]);
    l4[i] = f2bf(f[i] - bf2f(h[i]));
  }
  unsigned short* d = (unsigned short*)dst + (long)rrow * 3072;
  ushort4 hv = {h[0], h[1], h[2], h[3]};
  ushort4 lv = {l4[0], l4[1], l4[2], l4[3]};
  *(ushort4*)(d + c)        = hv;
  *(ushort4*)(d + 1024 + c) = APAT ? hv : lv;
  *(ushort4*)(d + 2048 + c) = APAT ? lv : hv;
}

// ---------- f32 -> bf16 vector cast ----------
__global__ __launch_bounds__(256) void k_cast4(const float* __restrict__ x,
                                               __hip_bfloat16* __restrict__ y, long n4) {
  long i = (long)blockIdx.x * 256 + threadIdx.x;
  if (i >= n4) return;
  float4 v = ((const float4*)x)[i];
  ushort4 o = {f2bf(v.x), f2bf(v.y), f2bf(v.z), f2bf(v.w)};
  ((ushort4*)y)[i] = o;
}

// ---------- pack Bbig[cat][n(2048)][k(2048)] from 4 weight tensors ----------
__global__ __launch_bounds__(256) void k_packBbig(const float* __restrict__ Ws2s,
                                                  const float* __restrict__ We2e,
                                                  const float* __restrict__ Ws2e,
                                                  const float* __restrict__ We2s,
                                                  __hip_bfloat16* __restrict__ dst) {
  long idx4 = ((long)blockIdx.x * 256 + threadIdx.x) * 4;
  long rowid = idx4 >> 11;
  int c = (int)(idx4 & 2047);
  int cat = (int)(rowid >> 11);
  int n = (int)(rowid & 2047);
  const float* src;
  if (n < 1024) src = (c < 1024) ? Ws2s + ((long)cat * 1024 + n) * 1024 + c
                                 : Ws2e + ((long)cat * 1024 + n) * 1024 + (c - 1024);
  else          src = (c < 1024) ? We2s + ((long)cat * 1024 + (n - 1024)) * 1024 + c
                                 : We2e + ((long)cat * 1024 + (n - 1024)) * 1024 + (c - 1024);
  float4 v = *(const float4*)src;
  ushort4 o = {f2bf(v.x), f2bf(v.y), f2bf(v.z), f2bf(v.w)};
  *(ushort4*)((unsigned short*)dst + idx4) = o;
}

// ---------- fused GELU+LN+rowdot+split3 for the s-half ----------
// reads se[r][0:1024] f32; writes ssp[r] = [hi|hi|lo] (3072 bf16) and smv[r]
__global__ __launch_bounds__(256) void k_ln_s(const float* __restrict__ se,
                                              const float* __restrict__ g,
                                              const float* __restrict__ beta,
                                              const float* __restrict__ wv,
                                              const float* __restrict__ b0,
                                              float* __restrict__ smv,
                                              __hip_bfloat16* __restrict__ ssp) {
  int r = blockIdx.x;
  int c4 = threadIdx.x;                       // float4 index 0..255
  float4 x = ((const float4*)(se + (long)r * 2048))[c4];
  float v[4] = {gelu_exact(x.x), gelu_exact(x.y), gelu_exact(x.z), gelu_exact(x.w)};
  float s = v[0] + v[1] + v[2] + v[3];
  float s2 = v[0]*v[0] + v[1]*v[1] + v[2]*v[2] + v[3]*v[3];
  __shared__ float red0[4], red1[4];
  for (int off = 32; off; off >>= 1) { s += __shfl_xor(s, off); s2 += __shfl_xor(s2, off); }
  int w = threadIdx.x >> 6;
  if ((threadIdx.x & 63) == 0) { red0[w] = s; red1[w] = s2; }
  __syncthreads();
  s  = red0[0] + red0[1] + red0[2] + red0[3];
  s2 = red1[0] + red1[1] + red1[2] + red1[3];
  float mu  = s / 1024.0f;
  float var = s2 / 1024.0f - mu * mu;
  float inv = 1.0f / sqrtf(var + 1e-5f);
  float4 gg = ((const float4*)g)[c4], bb = ((const float4*)beta)[c4];
  float y[4] = {(v[0]-mu)*inv*gg.x + bb.x, (v[1]-mu)*inv*gg.y + bb.y,
                (v[2]-mu)*inv*gg.z + bb.z, (v[3]-mu)*inv*gg.w + bb.w};
  // rowdot with wv
  float4 w4 = ((const float4*)wv)[c4];
  float d = y[0]*w4.x + y[1]*w4.y + y[2]*w4.z + y[3]*w4.w;
  for (int off = 32; off; off >>= 1) d += __shfl_xor(d, off);
  __syncthreads();
  if ((threadIdx.x & 63) == 0) red0[w] = d;
  __syncthreads();
  if (threadIdx.x == 0)
    smv[r] = red0[0] + red0[1] + red0[2] + red0[3] + b0[0];
  // split3 write [hi|hi|lo]
  unsigned short h[4], l4[4];
  #pragma unroll
  for (int i = 0; i < 4; ++i) { h[i] = f2bf(y[i]); l4[i] = f2bf(y[i] - bf2f(h[i])); }
  ushort4 hv = {h[0], h[1], h[2], h[3]};
  ushort4 lv = {l4[0], l4[1], l4[2], l4[3]};
  unsigned short* dst = (unsigned short*)ssp + (long)r * 3072 + c4 * 4;
  *(ushort4*)dst          = hv;
  *(ushort4*)(dst + 1024) = hv;
  *(ushort4*)(dst + 2048) = lv;
}

// ---------- fused GELU+LN+rowdot for the e-half (in-place f32) ----------
__global__ __launch_bounds__(256) void k_ln_e(float* __restrict__ se,
                                              const float* __restrict__ g,
                                              const float* __restrict__ beta,
                                              const float* __restrict__ wv,
                                              const float* __restrict__ b0,
                                              float* __restrict__ emv) {
  int r = blockIdx.x;
  int c4 = threadIdx.x;
  float4* rowp = (float4*)(se + (long)r * 2048 + 1024);
  float4 x = rowp[c4];
  float v[4] = {gelu_exact(x.x), gelu_exact(x.y), gelu_exact(x.z), gelu_exact(x.w)};
  float s = v[0] + v[1] + v[2] + v[3];
  float s2 = v[0]*v[0] + v[1]*v[1] + v[2]*v[2] + v[3]*v[3];
  __shared__ float red0[4], red1[4];
  for (int off = 32; off; off >>= 1) { s += __shfl_xor(s, off); s2 += __shfl_xor(s2, off); }
  int w = threadIdx.x >> 6;
  if ((threadIdx.x & 63) == 0) { red0[w] = s; red1[w] = s2; }
  __syncthreads();
  s  = red0[0] + red0[1] + red0[2] + red0[3];
  s2 = red1[0] + red1[1] + red1[2] + red1[3];
  float mu  = s / 1024.0f;
  float var = s2 / 1024.0f - mu * mu;
  float inv = 1.0f / sqrtf(var + 1e-5f);
  float4 gg = ((const float4*)g)[c4], bb = ((const float4*)beta)[c4];
  float4 y = {(v[0]-mu)*inv*gg.x + bb.x, (v[1]-mu)*inv*gg.y + bb.y,
              (v[2]-mu)*inv*gg.z + bb.z, (v[3]-mu)*inv*gg.w + bb.w};
  float4 w4 = ((const float4*)wv)[c4];
  float d = y.x*w4.x + y.y*w4.y + y.z*w4.z + y.w*w4.w;
  for (int off = 32; off; off >>= 1) d += __shfl_xor(d, off);
  __syncthreads();
  if ((threadIdx.x & 63) == 0) red0[w] = d;
  __syncthreads();
  if (threadIdx.x == 0)
    emv[r] = red0[0] + red0[1] + red0[2] + red0[3] + b0[0];
  rowp[c4] = y;
}

// ---------- GELU+LN over 7168 (bf16 in), write bf16 into a_cat[z][k][2048] half ----------
__global__ __launch_bounds__(256) void k_gelu_ln_cats(const __hip_bfloat16* __restrict__ h,
                                                      const float* __restrict__ g,
                                                      const float* __restrict__ beta,
                                                      __hip_bfloat16* __restrict__ a_cat, int half) {
  int r = blockIdx.x;                       // 0..2047
  int b = r >> 10, k = r & 1023;
  const ushort4* row = (const ushort4*)((const unsigned short*)h + (long)r * 7168);
  float v[28];
  float s = 0.f, s2 = 0.f;
  #pragma unroll
  for (int j = 0; j < 7; ++j) {
    ushort4 u = row[threadIdx.x + 256 * j];
    #pragma unroll
    for (int e = 0; e < 4; ++e) {
      float x = bf2f(((const unsigned short*)&u)[e]);
      float ge = gelu_exact(x);
      v[j * 4 + e] = ge; s += ge; s2 += ge * ge;
    }
  }
  __shared__ float red0[4], red1[4];
  for (int off = 32; off; off >>= 1) { s += __shfl_xor(s, off); s2 += __shfl_xor(s2, off); }
  int w = threadIdx.x >> 6;
  if ((threadIdx.x & 63) == 0) { red0[w] = s; red1[w] = s2; }
  __syncthreads();
  s  = red0[0] + red0[1] + red0[2] + red0[3];
  s2 = red1[0] + red1[1] + red1[2] + red1[3];
  float mu  = s / 7168.0f;
  float var = s2 / 7168.0f - mu * mu;
  float inv = 1.0f / sqrtf(var + 1e-5f);
  #pragma unroll
  for (int j = 0; j < 7; ++j) {
    int c0 = (threadIdx.x + 256 * j) * 4;
    int n = c0 >> 10, f = c0 & 1023;
    unsigned short o[4];
    #pragma unroll
    for (int e = 0; e < 4; ++e)
      o[e] = f2bf((v[j * 4 + e] - mu) * inv * g[c0 + e] + beta[c0 + e]);
    ushort4 ov = {o[0], o[1], o[2], o[3]};
    *(ushort4*)((unsigned short*)a_cat + ((long)((b * NC_ + n) * NK + k)) * 2048 + half * 1024 + f) = ov;
  }
}

// ---------- banded scores ----------
__global__ __launch_bounds__(256) void k_band(const float* __restrict__ s2m,
                                              const float* __restrict__ se,
                                              const float* __restrict__ smv,
                                              const float* __restrict__ emv,
                                              float* __restrict__ band) {
  __shared__ float s2row[1024];
  int bs = blockIdx.x;                 // b*2048+s
  const float* sp = s2m + (long)bs * 1024;
  for (int i = threadIdx.x; i < 1024; i += 256) s2row[i] = sp[i];
  __syncthreads();
  int b = bs >> 11, s = bs & 2047;
  int w = threadIdx.x >> 6, l = threadIdx.x & 63;
  for (int j = w; j < 32; j += 4) {
    int t = s + j;
    float val = -3.0e38f;
    if (j < 30 && t < S_) {
      const float4* ep = (const float4*)(se + ((long)((b << 11) + t)) * 2048 + 1024);
      const float4* zp = (const float4*)s2row;
      float acc = 0.f;
      #pragma unroll
      for (int qq = 0; qq < 4; ++qq) {
        float4 a = ep[l + 64 * qq], c = zp[l + 64 * qq];
        acc += a.x * c.x + a.y * c.y + a.z * c.z + a.w * c.w;
      }
      for (int off = 32; off; off >>= 1) acc += __shfl_xor(acc, off);
      val = acc + smv[bs] + emv[(b << 11) + t];
    }
    if (l == 0) band[(long)bs * 32 + j] = val;
  }
}

// ---------- exact top-k (radix select + bitonic), one block per batch ----------
__device__ __forceinline__ void bitonic1024(unsigned* buf) {
  int tid = threadIdx.x;
  __syncthreads();
  for (int k = 2; k <= 1024; k <<= 1)
    for (int j = k >> 1; j > 0; j >>= 1) {
      int ixj = tid ^ j;
      if (ixj > tid) {
        unsigned a = buf[tid], c = buf[ixj];
        bool up = ((tid & k) == 0);
        if (up ? (a > c) : (a < c)) { buf[tid] = c; buf[ixj] = a; }
      }
      __syncthreads();
    }
}

__global__ __launch_bounds__(1024) void k_topk(const float* __restrict__ band,
                                               const int* __restrict__ masks,
                                               int* __restrict__ starts, int* __restrict__ ends,
                                               float* __restrict__ tk, int* __restrict__ kvalid_out) {
  int b = blockIdx.x;
  const float* bb = band + (long)b * 65536;
  __shared__ unsigned hist[256];
  __shared__ int sh_digit, sh_R, sh_msum;
  __shared__ unsigned cntG, cntE;
  __shared__ unsigned listG[832];
  __shared__ unsigned listE[1024];
  __shared__ unsigned buf[1024];
  int tid = threadIdx.x;

  if (tid == 0) sh_msum = 0;
  __syncthreads();
  int pm = masks[b * S_ + tid] + masks[b * S_ + 1024 + tid];
  atomicAdd(&sh_msum, pm);
  __syncthreads();
  int kv = (int)((float)sh_msum * 0.4f);
  if (kv > MAXK) kv = MAXK;

  unsigned prefix = 0;
  int R = kv;
  if (kv > 0) {
    for (int shift = 24; shift >= 0; shift -= 8) {
      if (tid < 256) hist[tid] = 0;
      __syncthreads();
      for (int i = tid; i < 65536; i += 1024) {
        unsigned u = __float_as_uint(bb[i]);
        unsigned key = (u & 0x80000000u) ? ~u : (u | 0x80000000u);
        bool ok = (shift == 24) || ((key >> (shift + 8)) == (prefix >> (shift + 8)));
        if (ok) atomicAdd(&hist[(key >> shift) & 255u], 1u);
      }
      __syncthreads();
      if (tid == 0) {
        unsigned cum = 0; int d;
        for (d = 255; d >= 0; --d) {
          unsigned hc = hist[d];
          if (cum + hc >= (unsigned)R) break;
          cum += hc;
        }
        if (d < 0) d = 0;
        sh_digit = d; sh_R = R - (int)cum;
      }
      __syncthreads();
      prefix |= ((unsigned)sh_digit) << shift;
      R = sh_R;
      __syncthreads();
    }
  }
  if (tid == 0) { cntG = 0; cntE = 0; }
  __syncthreads();
  if (kv > 0) {
    for (int i = tid; i < 65536; i += 1024) {
      unsigned u = __float_as_uint(bb[i]);
      unsigned key = (u & 0x80000000u) ? ~u : (u | 0x80000000u);
      if (key > prefix) { unsigned p = atomicAdd(&cntG, 1u); if (p < 832) listG[p] = (unsigned)i; }
      else if (key == prefix) { unsigned p = atomicAdd(&cntE, 1u); if (p < 1024) listE[p] = (unsigned)i; }
    }
  }
  __syncthreads();
  int nG = (int)cntG, nE = (int)cntE, need = R;
  buf[tid] = (tid < nE) ? listE[tid] : 0xFFFFFFFFu;
  bitonic1024(buf);
  if (tid < need) listG[nG + tid] = buf[tid];
  __syncthreads();
  unsigned v2 = (tid < (unsigned)kv) ? listG[tid] : 0xFFFFFFFFu;
  __syncthreads();
  buf[tid] = v2;
  bitonic1024(buf);
  {
    int s, t; float val;
    if (tid < kv) {
      unsigned i = buf[tid];
      s = (int)(i >> 5); t = s + (int)(i & 31);
      val = bb[i];
    } else {
      s = S_ - 1; t = S_ - 1;
      val = bb[(S_ - 1) * 32 + 0];
    }
    starts[b * NK + tid] = s;
    ends[b * NK + tid] = t;
    tk[b * NK + tid] = val;
  }
  if (tid == 0) kvalid_out[b] = kv;
}

// ---------- gather span reps to bf16 ----------
__global__ __launch_bounds__(256) void k_gather(const float* __restrict__ emb,
                                                const int* __restrict__ starts,
                                                const int* __restrict__ ends,
                                                __hip_bfloat16* __restrict__ reps_s,
                                                __hip_bfloat16* __restrict__ reps_e) {
  int r = blockIdx.x;                 // b*NK + k
  int b = r >> 10;
  long ob = (long)r * 1024;
  const float4* ps = (const float4*)(emb + ((long)b * S_ + starts[r]) * 1024);
  const float4* pe = (const float4*)(emb + ((long)b * S_ + ends[r]) * 1024);
  unsigned short* ds = (unsigned short*)reps_s + ob;
  unsigned short* de = (unsigned short*)reps_e + ob;
  int c4 = threadIdx.x;
  float4 a = ps[c4], e = pe[c4];
  ushort4 oa = {f2bf(a.x), f2bf(a.y), f2bf(a.z), f2bf(a.w)};
  ushort4 oe = {f2bf(e.x), f2bf(e.y), f2bf(e.z), f2bf(e.w)};
  *(ushort4*)(ds + c4 * 4) = oa;
  *(ushort4*)(de + c4 * 4) = oe;
}

// ---------- antecedent bias vector (reads a_cat) ----------
__global__ __launch_bounds__(256) void k_bias(const __hip_bfloat16* __restrict__ a_cat,
                                              const float* __restrict__ Bs2s, const float* __restrict__ Be2e,
                                              const float* __restrict__ Bs2e, const float* __restrict__ Be2s,
                                              float* __restrict__ biasv) {
  int w = threadIdx.x >> 6, l = threadIdx.x & 63;
  int row = blockIdx.x * 4 + w;       // z*NK + lidx
  if (row >= Z_ * NK) return;
  int z = row >> 10, cat = z % NC_;
  const unsigned short* ar = (const unsigned short*)a_cat + (long)row * 2048;
  const float* b1 = Bs2s + cat * 1024;
  const float* b2 = Be2s + cat * 1024;
  const float* b3 = Be2e + cat * 1024;
  const float* b4 = Bs2e + cat * 1024;
  float acc = 0.f;
  for (int qq = 0; qq < 16; ++qq) {
    int c = l + 64 * qq;
    acc += bf2f(ar[c]) * (b1[c] + b2[c]);
    acc += bf2f(ar[1024 + c]) * (b3[c] + b4[c]);
  }
  for (int off = 32; off; off >>= 1) acc += __shfl_xor(acc, off);
  if (l == 0) biasv[row] = acc;
}

// =====================================================================
extern "C" void kernel_launch(void* const* d_in, const int* in_sizes, int n_in,
                              void* d_out, int out_size, void* d_ws, size_t ws_size,
                              hipStream_t stream) {
  const float* x_emb = (const float*)d_in[0];
  const int*   masks = (const int*)d_in[1];
  const float* smW  = (const float*)d_in[2];
  const float* smb  = (const float*)d_in[3];
  const float* smg  = (const float*)d_in[4];
  const float* smbe = (const float*)d_in[5];
  const float* emW  = (const float*)d_in[6];
  const float* embb = (const float*)d_in[7];
  const float* emg  = (const float*)d_in[8];
  const float* embe = (const float*)d_in[9];
  const float* msw  = (const float*)d_in[10];
  const float* msb  = (const float*)d_in[11];
  const float* mew  = (const float*)d_in[12];
  const float* meb  = (const float*)d_in[13];
  const float* s2eW = (const float*)d_in[14];
  const float* s2eb = (const float*)d_in[15];
  const float* csW  = (const float*)d_in[16];
  const float* csb  = (const float*)d_in[17];
  const float* csg  = (const float*)d_in[18];
  const float* csbe = (const float*)d_in[19];
  const float* ceW  = (const float*)d_in[20];
  const float* ceb  = (const float*)d_in[21];
  const float* ceg  = (const float*)d_in[22];
  const float* cebe = (const float*)d_in[23];
  const float* Ws2s = (const float*)d_in[24];
  const float* We2e = (const float*)d_in[25];
  const float* Ws2e = (const float*)d_in[26];
  const float* We2s = (const float*)d_in[27];
  const float* Bs2s = (const float*)d_in[28];
  const float* Be2e = (const float*)d_in[29];
  const float* Bs2e = (const float*)d_in[30];
  const float* Be2s = (const float*)d_in[31];
  float* outp = (float*)d_out;
  char* ws = (char*)d_ws;
  (void)in_sizes; (void)n_in; (void)out_size; (void)ws_size;

  // ---- workspace layout (liveness-aliased) ----
  const size_t o_embsp = 0;
  const size_t o_bse   = 25165824;
  const size_t o_ssp   = 0;
  const size_t o_s2W   = 25165824;
  const size_t o_repss = 0;
  const size_t o_repse = 4194304;
  const size_t o_csWb  = 8388608;
  const size_t o_ceWb  = 23068672;
  const size_t o_Bbig  = 0;
  const size_t o_se    = 37748736;   // 4096x2048 f32 = 33554432
  const size_t o_s2    = 71303168;   // 4096x1024 f32 = 16777216
  const size_t o_h     = 88080384;   // 2048x7168 bf16 = 29360128 ; later Vcat bf16 [14][1024][2048]
  const size_t o_acat  = 146800640;  // 14x1024x2048 bf16 = 58720256
  const size_t o_smv   = 205520896;
  const size_t o_emv   = o_smv + 16384;
  const size_t o_band  = o_emv + 16384;
  const size_t o_starts= o_band + 524288;
  const size_t o_ends  = o_starts + 8192;
  const size_t o_tk    = o_ends + 8192;
  const size_t o_kv    = o_tk + 8192;
  const size_t o_biasv = o_kv + 256;

  __hip_bfloat16* embsp = (__hip_bfloat16*)(ws + o_embsp);
  __hip_bfloat16* bse   = (__hip_bfloat16*)(ws + o_bse);
  __hip_bfloat16* ssp   = (__hip_bfloat16*)(ws + o_ssp);
  __hip_bfloat16* s2Wsp = (__hip_bfloat16*)(ws + o_s2W);
  __hip_bfloat16* repss = (__hip_bfloat16*)(ws + o_repss);
  __hip_bfloat16* repse = (__hip_bfloat16*)(ws + o_repse);
  __hip_bfloat16* csWb  = (__hip_bfloat16*)(ws + o_csWb);
  __hip_bfloat16* ceWb  = (__hip_bfloat16*)(ws + o_ceWb);
  __hip_bfloat16* Bbig  = (__hip_bfloat16*)(ws + o_Bbig);
  float* se_buf = (float*)(ws + o_se);
  float* s2_buf = (float*)(ws + o_s2);
  __hip_bfloat16* h_buf = (__hip_bfloat16*)(ws + o_h);
  __hip_bfloat16* Vcat  = (__hip_bfloat16*)(ws + o_h);
  __hip_bfloat16* a_cat = (__hip_bfloat16*)(ws + o_acat);
  float* smv_p = (float*)(ws + o_smv);
  float* emv_p = (float*)(ws + o_emv);
  float* band_p = (float*)(ws + o_band);
  int* starts_p = (int*)(ws + o_starts);
  int* ends_p = (int*)(ws + o_ends);
  float* tk_p = (float*)(ws + o_tk);
  int* kv_p = (int*)(ws + o_kv);
  float* biasv_p = (float*)(ws + o_biasv);

  // ---- stage A: se = [emb@smW^T | emb@emW^T] via split3 K-concat (f32-grade) ----
  k_packsplit3<true ><<<4096, 256, 0, stream>>>(x_emb, 1024, x_emb, 4096, embsp);
  k_packsplit3<false><<<2048, 256, 0, stream>>>(smW, 1024, emW, 1024, bse);
  k_gemm8<false, 1><<<dim3(128, 1, 1), 512, 0, stream>>>(embsp, bse, se_buf, smb, embb,
      nullptr, nullptr, 3072, 8, 0, 0, 0, 0, 2048, 4096, 2048);
  // fused GELU+LN+rowdot(+split3 for s) over each half
  k_ln_s<<<4096, 256, 0, stream>>>(se_buf, smg, smbe, msw, msb, smv_p, ssp);
  k_ln_e<<<4096, 256, 0, stream>>>(se_buf, emg, embe, mew, meb, emv_p);

  // ---- stage C: s2 = s@s2eW^T + b ; banded scores ----
  k_packsplit3<false><<<1024, 256, 0, stream>>>(s2eW, 1024, s2eW, 1024, s2Wsp);
  k_gemm8<false, 0><<<dim3(64, 1, 1), 512, 0, stream>>>(ssp, s2Wsp, s2_buf, s2eb, nullptr,
      nullptr, nullptr, 3072, 4, 0, 0, 0, 0, 1024, 4096, 1024);
  k_band<<<4096, 256, 0, stream>>>(s2_buf, se_buf, smv_p, emv_p, band_p);

  // ---- stage D: exact top-k ----
  k_topk<<<2, 1024, 0, stream>>>(band_p, masks, starts_p, ends_p, tk_p, kv_p);

  // ---- stage E/F: gather + FC to per-category reps ----
  k_gather<<<2 * NK, 256, 0, stream>>>(x_emb, starts_p, ends_p, repss, repse);
  k_cast4<<<7168, 256, 0, stream>>>(csW, csWb, 1835008);
  k_cast4<<<7168, 256, 0, stream>>>(ceW, ceWb, 1835008);
  k_gemm8<true, 0><<<dim3(224, 1, 1), 512, 0, stream>>>(repss, csWb, h_buf, csb, nullptr,
      nullptr, nullptr, 1024, 28, 0, 0, 0, 0, 7168, 2048, 7168);
  k_gelu_ln_cats<<<2048, 256, 0, stream>>>(h_buf, csg, csbe, a_cat, 0);
  k_gemm8<true, 0><<<dim3(224, 1, 1), 512, 0, stream>>>(repse, ceWb, h_buf, ceb, nullptr,
      nullptr, nullptr, 1024, 28, 0, 0, 0, 0, 7168, 2048, 7168);
  k_packBbig<<<28672, 256, 0, stream>>>(Ws2s, We2e, Ws2e, We2s, Bbig);
  k_gelu_ln_cats<<<2048, 256, 0, stream>>>(h_buf, ceg, cebe, a_cat, 1);

  // ---- stage G: Vcat = a_cat @ Bbig^T (per z, cat = z%7), then logits ----
  k_gemm8<true, 0><<<dim3(32, 1, Z_), 512, 0, stream>>>(a_cat, Bbig, Vcat, nullptr, nullptr,
      nullptr, nullptr, 2048, 8, (long)NK * 2048, (long)2048 * 2048, 1, (long)NK * 2048, 2048, NK, 2048);
  k_bias<<<(Z_ * NK) / 4, 256, 0, stream>>>(a_cat, Bs2s, Be2e, Bs2e, Be2s, biasv_p);
  // logits + fused epilogue (bias[l] + pair + mask) straight into d_out
  k_gemm8<false, 2><<<dim3(16, 1, Z_), 512, 0, stream>>>(a_cat, Vcat, outp, biasv_p, nullptr,
      tk_p, kv_p, 2048, 4, (long)NK * 2048, (long)NK * 2048, 0, (long)MAXK * MAXK, MAXK, MAXK, MAXK);
}

// Round 5
// 835.875 us; speedup vs baseline: 1.0473x; 1.0473x over previous
//
#include <hip/hip_runtime.h>
#include <hip/hip_bf16.h>
#include <math.h>

// ---- problem constants ----
#define S_    2048
#define NC_   7
#define MAXK  819
#define NK    1024          // padded top-k rows (4*256)
#define Z_    14            // B*NUM_CATS
#define NEGV  (-10000.0f)

typedef __attribute__((ext_vector_type(8))) short bf16x8;
typedef __attribute__((ext_vector_type(4))) float f32x4;

__device__ __forceinline__ void gload_lds16(const void* g, void* l) {
  __builtin_amdgcn_global_load_lds((const __attribute__((address_space(1))) unsigned int*)g,
                                   (__attribute__((address_space(3))) unsigned int*)l, 16, 0, 0);
}

__device__ __forceinline__ float gelu_exact(float x) {
  return 0.5f * x * (1.0f + erff(x * 0.70710678118654752f));
}
__device__ __forceinline__ unsigned short f2bf(float x) {
  __hip_bfloat16 h = __float2bfloat16(x);
  return *(unsigned short*)&h;
}
__device__ __forceinline__ float bf2f(unsigned short u) {
  __hip_bfloat16 h; *(unsigned short*)&h = u;
  return __bfloat162float(h);
}

// ============ m97-replica 128x128 GEMM, 4 waves, BK=32, 3 blocks/CU ============
// C[m,n] = sum_k A[m,k]*B[n,k]  (both row-major with K inner)
// EPI 0: optional bias1[n]; EPI 1: bias1/bias2 split at n=1024; EPI 2: logits epilogue
template<bool OBF16, int EPI>
__global__ __launch_bounds__(256, 3) void k_gemm97(
    const __hip_bfloat16* __restrict__ A, const __hip_bfloat16* __restrict__ B,
    void* __restrict__ Cv, const float* __restrict__ bias1, const float* __restrict__ bias2,
    const float* __restrict__ tkv, const int* __restrict__ kvp,
    int K, int nbn, long strideA, long strideB, int bmod7, long strideC,
    int ldc, int Mstore, int Nstore)
{
  __shared__ __align__(16) char lds[16384];   // A[0,8K) B[8K,16K)
  const int tid = threadIdx.x;
  const int z = blockIdx.z;
  // bijective XCD swizzle (m204)
  const int nwg = gridDim.x;
  const int xcd = blockIdx.x & 7, loc = blockIdx.x >> 3;
  const int q = nwg >> 3, r = nwg & 7;
  const int wg = (xcd < r ? xcd * (q + 1) : r * (q + 1) + (xcd - r) * q) + loc;
  const int bm = wg / nbn, bn = wg % nbn;
  const int m0 = bm * 128, n0 = bn * 128;
  const __hip_bfloat16* pA = A + (long)z * strideA;
  const __hip_bfloat16* pB = B + (long)(bmod7 ? (z % 7) : z) * strideB;
  const int wave = tid >> 6, lane = tid & 63;
  const int wr = wave >> 1, wc = wave & 1;
  const int lr = lane & 15, kh = lane >> 4;
  const long Kb = (long)K * 2;

  f32x4 acc[4][4];
  #pragma unroll
  for (int i = 0; i < 4; ++i)
    #pragma unroll
    for (int j = 0; j < 4; ++j)
      #pragma unroll
      for (int rr = 0; rr < 4; ++rr) acc[i][j][rr] = 0.0f;

  const int nk = K >> 5;
  for (int kt = 0; kt < nk; ++kt) {
    const long kbyte = (long)kt * 64;
    #pragma unroll
    for (int j = 0; j < 2; ++j) {
      int off = j * 4096 + tid * 16;
      int row = off >> 6, col = off & 63;
      int gc = col ^ ((row & 3) << 4);          // inverse swizzle on global source
      gload_lds16((const char*)pA + (long)(m0 + row) * Kb + kbyte + gc, &lds[off]);
      gload_lds16((const char*)pB + (long)(n0 + row) * Kb + kbyte + gc, &lds[8192 + off]);
    }
    __syncthreads();    // drains vmcnt (m97 structure)

    bf16x8 af[4], bfr[4];
    #pragma unroll
    for (int mi = 0; mi < 4; ++mi) {
      int row = wr * 64 + mi * 16 + lr;
      af[mi] = *(const bf16x8*)&lds[row * 64 + ((kh * 16) ^ ((row & 3) << 4))];
    }
    #pragma unroll
    for (int ni = 0; ni < 4; ++ni) {
      int row = wc * 64 + ni * 16 + lr;
      bfr[ni] = *(const bf16x8*)&lds[8192 + row * 64 + ((kh * 16) ^ ((row & 3) << 4))];
    }
    #pragma unroll
    for (int mi = 0; mi < 4; ++mi)
      #pragma unroll
      for (int ni = 0; ni < 4; ++ni)
        acc[mi][ni] = __builtin_amdgcn_mfma_f32_16x16x32_bf16(af[mi], bfr[ni], acc[mi][ni], 0, 0, 0);
    __syncthreads();
  }

  const long coff = (long)z * strideC;
  int kval = 0, bb_ = 0;
  if (EPI == 2) { bb_ = z / NC_; kval = kvp[bb_]; }
  #pragma unroll
  for (int mi = 0; mi < 4; ++mi) {
    #pragma unroll
    for (int ni = 0; ni < 4; ++ni) {
      int n = n0 + wc * 64 + ni * 16 + lr;
      if (n >= Nstore) continue;
      float badd = 0.f;
      if (EPI == 0) { if (bias1) badd = bias1[n]; }
      if (EPI == 1) badd = (n >= 1024) ? bias2[n - 1024] : bias1[n];
      if (EPI == 2) badd = bias1[z * NK + n] + tkv[bb_ * NK + n];
      #pragma unroll
      for (int rr = 0; rr < 4; ++rr) {
        int m = m0 + wr * 64 + mi * 16 + kh * 4 + rr;
        if (m >= Mstore) continue;
        float v = acc[mi][ni][rr] + badd;
        if (EPI == 2) {
          v += tkv[bb_ * NK + m];
          if (!(n < m && n < kval)) v += NEGV;
        }
        if (OBF16) ((__hip_bfloat16*)Cv)[coff + (long)m * ldc + n] = __float2bfloat16(v);
        else       ((float*)Cv)[coff + (long)m * ldc + n] = v;
      }
    }
  }
}

// ---------- pack split3: dst rows 3072 wide. APAT: [hi|hi|lo]; else [hi|lo|hi] ----------
template<bool APAT>
__global__ __launch_bounds__(256) void k_packsplit3(const float* __restrict__ s1, long stride1,
                                                    const float* __restrict__ s2, int split,
                                                    __hip_bfloat16* __restrict__ dst) {
  long idx4 = ((long)blockIdx.x * 256 + threadIdx.x) * 4;
  int rrow = (int)(idx4 >> 10), c = (int)(idx4 & 1023);
  const float* src = (rrow < split) ? s1 + (long)rrow * stride1 + c
                                    : s2 + (long)(rrow - split) * 1024 + c;
  float4 v = *(const float4*)src;
  float f[4] = {v.x, v.y, v.z, v.w};
  unsigned short h[4], l4[4];
  #pragma unroll
  for (int i = 0; i < 4; ++i) {
    h[i] = f2bf(f[i]);
    l4[i] = f2bf(f[i] - bf2f(h[i]));
  }
  unsigned short* d = (unsigned short*)dst + (long)rrow * 3072;
  ushort4 hv = {h[0], h[1], h[2], h[3]};
  ushort4 lv = {l4[0], l4[1], l4[2], l4[3]};
  *(ushort4*)(d + c)        = hv;
  *(ushort4*)(d + 1024 + c) = APAT ? hv : lv;
  *(ushort4*)(d + 2048 + c) = APAT ? lv : hv;
}

// ---------- f32 -> bf16 vector cast ----------
__global__ __launch_bounds__(256) void k_cast4(const float* __restrict__ x,
                                               __hip_bfloat16* __restrict__ y, long n4) {
  long i = (long)blockIdx.x * 256 + threadIdx.x;
  if (i >= n4) return;
  float4 v = ((const float4*)x)[i];
  ushort4 o = {f2bf(v.x), f2bf(v.y), f2bf(v.z), f2bf(v.w)};
  ((ushort4*)y)[i] = o;
}

// ---------- pack Bbig[cat][n(2048)][k(2048)] from 4 weight tensors ----------
__global__ __launch_bounds__(256) void k_packBbig(const float* __restrict__ Ws2s,
                                                  const float* __restrict__ We2e,
                                                  const float* __restrict__ Ws2e,
                                                  const float* __restrict__ We2s,
                                                  __hip_bfloat16* __restrict__ dst) {
  long idx4 = ((long)blockIdx.x * 256 + threadIdx.x) * 4;
  long rowid = idx4 >> 11;
  int c = (int)(idx4 & 2047);
  int cat = (int)(rowid >> 11);
  int n = (int)(rowid & 2047);
  const float* src;
  if (n < 1024) src = (c < 1024) ? Ws2s + ((long)cat * 1024 + n) * 1024 + c
                                 : Ws2e + ((long)cat * 1024 + n) * 1024 + (c - 1024);
  else          src = (c < 1024) ? We2s + ((long)cat * 1024 + (n - 1024)) * 1024 + c
                                 : We2e + ((long)cat * 1024 + (n - 1024)) * 1024 + (c - 1024);
  float4 v = *(const float4*)src;
  ushort4 o = {f2bf(v.x), f2bf(v.y), f2bf(v.z), f2bf(v.w)};
  *(ushort4*)((unsigned short*)dst + idx4) = o;
}

// ---------- fused GELU+LN+rowdot+split3 for the s-half ----------
__global__ __launch_bounds__(256) void k_ln_s(const float* __restrict__ se,
                                              const float* __restrict__ g,
                                              const float* __restrict__ beta,
                                              const float* __restrict__ wv,
                                              const float* __restrict__ b0,
                                              float* __restrict__ smv,
                                              __hip_bfloat16* __restrict__ ssp) {
  int r = blockIdx.x;
  int c4 = threadIdx.x;                       // float4 index 0..255
  float4 x = ((const float4*)(se + (long)r * 2048))[c4];
  float v[4] = {gelu_exact(x.x), gelu_exact(x.y), gelu_exact(x.z), gelu_exact(x.w)};
  float s = v[0] + v[1] + v[2] + v[3];
  float s2 = v[0]*v[0] + v[1]*v[1] + v[2]*v[2] + v[3]*v[3];
  __shared__ float red0[4], red1[4];
  for (int off = 32; off; off >>= 1) { s += __shfl_xor(s, off); s2 += __shfl_xor(s2, off); }
  int w = threadIdx.x >> 6;
  if ((threadIdx.x & 63) == 0) { red0[w] = s; red1[w] = s2; }
  __syncthreads();
  s  = red0[0] + red0[1] + red0[2] + red0[3];
  s2 = red1[0] + red1[1] + red1[2] + red1[3];
  float mu  = s / 1024.0f;
  float var = s2 / 1024.0f - mu * mu;
  float inv = 1.0f / sqrtf(var + 1e-5f);
  float4 gg = ((const float4*)g)[c4], bb = ((const float4*)beta)[c4];
  float y[4] = {(v[0]-mu)*inv*gg.x + bb.x, (v[1]-mu)*inv*gg.y + bb.y,
                (v[2]-mu)*inv*gg.z + bb.z, (v[3]-mu)*inv*gg.w + bb.w};
  float4 w4 = ((const float4*)wv)[c4];
  float d = y[0]*w4.x + y[1]*w4.y + y[2]*w4.z + y[3]*w4.w;
  for (int off = 32; off; off >>= 1) d += __shfl_xor(d, off);
  __syncthreads();
  if ((threadIdx.x & 63) == 0) red0[w] = d;
  __syncthreads();
  if (threadIdx.x == 0)
    smv[r] = red0[0] + red0[1] + red0[2] + red0[3] + b0[0];
  unsigned short h[4], l4[4];
  #pragma unroll
  for (int i = 0; i < 4; ++i) { h[i] = f2bf(y[i]); l4[i] = f2bf(y[i] - bf2f(h[i])); }
  ushort4 hv = {h[0], h[1], h[2], h[3]};
  ushort4 lv = {l4[0], l4[1], l4[2], l4[3]};
  unsigned short* dst = (unsigned short*)ssp + (long)r * 3072 + c4 * 4;
  *(ushort4*)dst          = hv;
  *(ushort4*)(dst + 1024) = hv;
  *(ushort4*)(dst + 2048) = lv;
}

// ---------- fused GELU+LN+rowdot for the e-half (in-place f32) ----------
__global__ __launch_bounds__(256) void k_ln_e(float* __restrict__ se,
                                              const float* __restrict__ g,
                                              const float* __restrict__ beta,
                                              const float* __restrict__ wv,
                                              const float* __restrict__ b0,
                                              float* __restrict__ emv) {
  int r = blockIdx.x;
  int c4 = threadIdx.x;
  float4* rowp = (float4*)(se + (long)r * 2048 + 1024);
  float4 x = rowp[c4];
  float v[4] = {gelu_exact(x.x), gelu_exact(x.y), gelu_exact(x.z), gelu_exact(x.w)};
  float s = v[0] + v[1] + v[2] + v[3];
  float s2 = v[0]*v[0] + v[1]*v[1] + v[2]*v[2] + v[3]*v[3];
  __shared__ float red0[4], red1[4];
  for (int off = 32; off; off >>= 1) { s += __shfl_xor(s, off); s2 += __shfl_xor(s2, off); }
  int w = threadIdx.x >> 6;
  if ((threadIdx.x & 63) == 0) { red0[w] = s; red1[w] = s2; }
  __syncthreads();
  s  = red0[0] + red0[1] + red0[2] + red0[3];
  s2 = red1[0] + red1[1] + red1[2] + red1[3];
  float mu  = s / 1024.0f;
  float var = s2 / 1024.0f - mu * mu;
  float inv = 1.0f / sqrtf(var + 1e-5f);
  float4 gg = ((const float4*)g)[c4], bb = ((const float4*)beta)[c4];
  float4 y = {(v[0]-mu)*inv*gg.x + bb.x, (v[1]-mu)*inv*gg.y + bb.y,
              (v[2]-mu)*inv*gg.z + bb.z, (v[3]-mu)*inv*gg.w + bb.w};
  float4 w4 = ((const float4*)wv)[c4];
  float d = y.x*w4.x + y.y*w4.y + y.z*w4.z + y.w*w4.w;
  for (int off = 32; off; off >>= 1) d += __shfl_xor(d, off);
  __syncthreads();
  if ((threadIdx.x & 63) == 0) red0[w] = d;
  __syncthreads();
  if (threadIdx.x == 0)
    emv[r] = red0[0] + red0[1] + red0[2] + red0[3] + b0[0];
  rowp[c4] = y;
}

// ---------- GELU+LN over 7168 (bf16 in), write bf16 into a_cat[z][k][2048] half ----------
__global__ __launch_bounds__(256) void k_gelu_ln_cats(const __hip_bfloat16* __restrict__ h,
                                                      const float* __restrict__ g,
                                                      const float* __restrict__ beta,
                                                      __hip_bfloat16* __restrict__ a_cat, int half) {
  int r = blockIdx.x;                       // 0..2047
  int b = r >> 10, k = r & 1023;
  const ushort4* row = (const ushort4*)((const unsigned short*)h + (long)r * 7168);
  float v[28];
  float s = 0.f, s2 = 0.f;
  #pragma unroll
  for (int j = 0; j < 7; ++j) {
    ushort4 u = row[threadIdx.x + 256 * j];
    #pragma unroll
    for (int e = 0; e < 4; ++e) {
      float x = bf2f(((const unsigned short*)&u)[e]);
      float ge = gelu_exact(x);
      v[j * 4 + e] = ge; s += ge; s2 += ge * ge;
    }
  }
  __shared__ float red0[4], red1[4];
  for (int off = 32; off; off >>= 1) { s += __shfl_xor(s, off); s2 += __shfl_xor(s2, off); }
  int w = threadIdx.x >> 6;
  if ((threadIdx.x & 63) == 0) { red0[w] = s; red1[w] = s2; }
  __syncthreads();
  s  = red0[0] + red0[1] + red0[2] + red0[3];
  s2 = red1[0] + red1[1] + red1[2] + red1[3];
  float mu  = s / 7168.0f;
  float var = s2 / 7168.0f - mu * mu;
  float inv = 1.0f / sqrtf(var + 1e-5f);
  #pragma unroll
  for (int j = 0; j < 7; ++j) {
    int c0 = (threadIdx.x + 256 * j) * 4;
    int n = c0 >> 10, f = c0 & 1023;
    unsigned short o[4];
    #pragma unroll
    for (int e = 0; e < 4; ++e)
      o[e] = f2bf((v[j * 4 + e] - mu) * inv * g[c0 + e] + beta[c0 + e]);
    ushort4 ov = {o[0], o[1], o[2], o[3]};
    *(ushort4*)((unsigned short*)a_cat + ((long)((b * NC_ + n) * NK + k)) * 2048 + half * 1024 + f) = ov;
  }
}

// ---------- banded scores: 8 s-rows per block, e-rows staged via LDS ----------
__global__ __launch_bounds__(512) void k_band(const float* __restrict__ s2m,
                                              const float* __restrict__ se,
                                              const float* __restrict__ smv,
                                              const float* __restrict__ emv,
                                              float* __restrict__ band) {
  __shared__ float ebuf[2][1024];
  int blk = blockIdx.x;                 // 0..511
  int b = blk >> 8;
  int s0 = (blk & 255) * 8;
  int w = threadIdx.x >> 6, l = threadIdx.x & 63;
  int s = s0 + w;
  int tid = threadIdx.x;
  // s2 row of this wave's s into registers
  float sreg[16];
  const float* sp = s2m + ((long)(b << 11) + s) * 1024;
  #pragma unroll
  for (int qq = 0; qq < 16; ++qq) sreg[qq] = sp[l + 64 * qq];
  float myS = smv[(b << 11) + s];
  // sentinels for invalid j slots
  if (l < 32) {
    int j = l;
    if (j >= 30 || s + j >= S_)
      band[((long)(b << 11) + s) * 32 + j] = -3.0e38f;
  }
  // preload t = s0
  {
    const float* ep = se + ((long)(b << 11) + s0) * 2048 + 1024;
    ebuf[0][tid * 2]     = ep[tid * 2];
    ebuf[0][tid * 2 + 1] = ep[tid * 2 + 1];
  }
  for (int it = 0; it < 37; ++it) {
    int t = s0 + it;
    __syncthreads();
    if (it + 1 < 37 && s0 + it + 1 < S_) {
      const float* ep = se + ((long)(b << 11) + s0 + it + 1) * 2048 + 1024;
      ebuf[(it + 1) & 1][tid * 2]     = ep[tid * 2];
      ebuf[(it + 1) & 1][tid * 2 + 1] = ep[tid * 2 + 1];
    }
    int j = t - s;
    if (t < S_ && j >= 0 && j < 30) {
      const float* eb = ebuf[it & 1];
      float acc = 0.f;
      #pragma unroll
      for (int qq = 0; qq < 16; ++qq) acc += sreg[qq] * eb[l + 64 * qq];
      for (int off = 32; off; off >>= 1) acc += __shfl_xor(acc, off);
      if (l == 0)
        band[((long)(b << 11) + s) * 32 + j] = acc + myS + emv[(b << 11) + t];
    }
  }
}

// ---------- exact top-k (radix select + bitonic), one block per batch ----------
__device__ __forceinline__ void bitonic1024(unsigned* buf) {
  int tid = threadIdx.x;
  __syncthreads();
  for (int k = 2; k <= 1024; k <<= 1)
    for (int j = k >> 1; j > 0; j >>= 1) {
      int ixj = tid ^ j;
      if (ixj > tid) {
        unsigned a = buf[tid], c = buf[ixj];
        bool up = ((tid & k) == 0);
        if (up ? (a > c) : (a < c)) { buf[tid] = c; buf[ixj] = a; }
      }
      __syncthreads();
    }
}

__global__ __launch_bounds__(1024) void k_topk(const float* __restrict__ band,
                                               const int* __restrict__ masks,
                                               int* __restrict__ starts, int* __restrict__ ends,
                                               float* __restrict__ tk, int* __restrict__ kvalid_out) {
  int b = blockIdx.x;
  const float* bb = band + (long)b * 65536;
  __shared__ unsigned hist[16][256];      // per-wave privatized
  __shared__ int sh_digit, sh_R, sh_msum;
  __shared__ unsigned cntG, cntE;
  __shared__ unsigned listG[832];
  __shared__ unsigned listE[1024];
  __shared__ unsigned buf[1024];
  int tid = threadIdx.x;
  int wv = tid >> 6;

  if (tid == 0) sh_msum = 0;
  __syncthreads();
  int pm = masks[b * S_ + tid] + masks[b * S_ + 1024 + tid];
  atomicAdd(&sh_msum, pm);
  __syncthreads();
  int kv = (int)((float)sh_msum * 0.4f);
  if (kv > MAXK) kv = MAXK;

  unsigned prefix = 0;
  int R = kv;
  if (kv > 0) {
    for (int shift = 24; shift >= 0; shift -= 8) {
      for (int i = tid; i < 4096; i += 1024) ((unsigned*)hist)[i] = 0;
      __syncthreads();
      for (int i = tid; i < 65536; i += 1024) {
        unsigned u = __float_as_uint(bb[i]);
        unsigned key = (u & 0x80000000u) ? ~u : (u | 0x80000000u);
        bool ok = (shift == 24) || ((key >> (shift + 8)) == (prefix >> (shift + 8)));
        if (ok) atomicAdd(&hist[wv][(key >> shift) & 255u], 1u);
      }
      __syncthreads();
      if (tid < 256) {
        unsigned sacc = 0;
        #pragma unroll
        for (int ww = 0; ww < 16; ++ww) sacc += hist[ww][tid];
        hist[0][tid] = sacc;
      }
      __syncthreads();
      if (tid == 0) {
        unsigned cum = 0; int d;
        for (d = 255; d >= 0; --d) {
          unsigned hc = hist[0][d];
          if (cum + hc >= (unsigned)R) break;
          cum += hc;
        }
        if (d < 0) d = 0;
        sh_digit = d; sh_R = R - (int)cum;
      }
      __syncthreads();
      prefix |= ((unsigned)sh_digit) << shift;
      R = sh_R;
      __syncthreads();
    }
  }
  if (tid == 0) { cntG = 0; cntE = 0; }
  __syncthreads();
  if (kv > 0) {
    for (int i = tid; i < 65536; i += 1024) {
      unsigned u = __float_as_uint(bb[i]);
      unsigned key = (u & 0x80000000u) ? ~u : (u | 0x80000000u);
      if (key > prefix) { unsigned p = atomicAdd(&cntG, 1u); if (p < 832) listG[p] = (unsigned)i; }
      else if (key == prefix) { unsigned p = atomicAdd(&cntE, 1u); if (p < 1024) listE[p] = (unsigned)i; }
    }
  }
  __syncthreads();
  int nG = (int)cntG, nE = (int)cntE, need = R;
  buf[tid] = (tid < nE) ? listE[tid] : 0xFFFFFFFFu;
  bitonic1024(buf);
  if (tid < need) listG[nG + tid] = buf[tid];
  __syncthreads();
  unsigned v2 = (tid < (unsigned)kv) ? listG[tid] : 0xFFFFFFFFu;
  __syncthreads();
  buf[tid] = v2;
  bitonic1024(buf);
  {
    int s, t; float val;
    if (tid < kv) {
      unsigned i = buf[tid];
      s = (int)(i >> 5); t = s + (int)(i & 31);
      val = bb[i];
    } else {
      s = S_ - 1; t = S_ - 1;
      val = bb[(S_ - 1) * 32 + 0];
    }
    starts[b * NK + tid] = s;
    ends[b * NK + tid] = t;
    tk[b * NK + tid] = val;
  }
  if (tid == 0) kvalid_out[b] = kv;
}

// ---------- gather span reps to bf16 ----------
__global__ __launch_bounds__(256) void k_gather(const float* __restrict__ emb,
                                                const int* __restrict__ starts,
                                                const int* __restrict__ ends,
                                                __hip_bfloat16* __restrict__ reps_s,
                                                __hip_bfloat16* __restrict__ reps_e) {
  int r = blockIdx.x;                 // b*NK + k
  int b = r >> 10;
  long ob = (long)r * 1024;
  const float4* ps = (const float4*)(emb + ((long)b * S_ + starts[r]) * 1024);
  const float4* pe = (const float4*)(emb + ((long)b * S_ + ends[r]) * 1024);
  unsigned short* ds = (unsigned short*)reps_s + ob;
  unsigned short* de = (unsigned short*)reps_e + ob;
  int c4 = threadIdx.x;
  float4 a = ps[c4], e = pe[c4];
  ushort4 oa = {f2bf(a.x), f2bf(a.y), f2bf(a.z), f2bf(a.w)};
  ushort4 oe = {f2bf(e.x), f2bf(e.y), f2bf(e.z), f2bf(e.w)};
  *(ushort4*)(ds + c4 * 4) = oa;
  *(ushort4*)(de + c4 * 4) = oe;
}

// ---------- antecedent bias vector (reads a_cat) ----------
__global__ __launch_bounds__(256) void k_bias(const __hip_bfloat16* __restrict__ a_cat,
                                              const float* __restrict__ Bs2s, const float* __restrict__ Be2e,
                                              const float* __restrict__ Bs2e, const float* __restrict__ Be2s,
                                              float* __restrict__ biasv) {
  int w = threadIdx.x >> 6, l = threadIdx.x & 63;
  int row = blockIdx.x * 4 + w;       // z*NK + lidx
  if (row >= Z_ * NK) return;
  int z = row >> 10, cat = z % NC_;
  const unsigned short* ar = (const unsigned short*)a_cat + (long)row * 2048;
  const float* b1 = Bs2s + cat * 1024;
  const float* b2 = Be2s + cat * 1024;
  const float* b3 = Be2e + cat * 1024;
  const float* b4 = Bs2e + cat * 1024;
  float acc = 0.f;
  for (int qq = 0; qq < 16; ++qq) {
    int c = l + 64 * qq;
    acc += bf2f(ar[c]) * (b1[c] + b2[c]);
    acc += bf2f(ar[1024 + c]) * (b3[c] + b4[c]);
  }
  for (int off = 32; off; off >>= 1) acc += __shfl_xor(acc, off);
  if (l == 0) biasv[row] = acc;
}

// =====================================================================
extern "C" void kernel_launch(void* const* d_in, const int* in_sizes, int n_in,
                              void* d_out, int out_size, void* d_ws, size_t ws_size,
                              hipStream_t stream) {
  const float* x_emb = (const float*)d_in[0];
  const int*   masks = (const int*)d_in[1];
  const float* smW  = (const float*)d_in[2];
  const float* smb  = (const float*)d_in[3];
  const float* smg  = (const float*)d_in[4];
  const float* smbe = (const float*)d_in[5];
  const float* emW  = (const float*)d_in[6];
  const float* embb = (const float*)d_in[7];
  const float* emg  = (const float*)d_in[8];
  const float* embe = (const float*)d_in[9];
  const float* msw  = (const float*)d_in[10];
  const float* msb  = (const float*)d_in[11];
  const float* mew  = (const float*)d_in[12];
  const float* meb  = (const float*)d_in[13];
  const float* s2eW = (const float*)d_in[14];
  const float* s2eb = (const float*)d_in[15];
  const float* csW  = (const float*)d_in[16];
  const float* csb  = (const float*)d_in[17];
  const float* csg  = (const float*)d_in[18];
  const float* csbe = (const float*)d_in[19];
  const float* ceW  = (const float*)d_in[20];
  const float* ceb  = (const float*)d_in[21];
  const float* ceg  = (const float*)d_in[22];
  const float* cebe = (const float*)d_in[23];
  const float* Ws2s = (const float*)d_in[24];
  const float* We2e = (const float*)d_in[25];
  const float* Ws2e = (const float*)d_in[26];
  const float* We2s = (const float*)d_in[27];
  const float* Bs2s = (const float*)d_in[28];
  const float* Be2e = (const float*)d_in[29];
  const float* Bs2e = (const float*)d_in[30];
  const float* Be2s = (const float*)d_in[31];
  float* outp = (float*)d_out;
  char* ws = (char*)d_ws;
  (void)in_sizes; (void)n_in; (void)out_size; (void)ws_size;

  // ---- workspace layout (liveness-aliased) ----
  const size_t o_embsp = 0;
  const size_t o_bse   = 25165824;
  const size_t o_ssp   = 0;
  const size_t o_s2W   = 25165824;
  const size_t o_repss = 0;
  const size_t o_repse = 4194304;
  const size_t o_csWb  = 8388608;
  const size_t o_ceWb  = 23068672;
  const size_t o_Bbig  = 0;
  const size_t o_se    = 37748736;   // 4096x2048 f32 = 33554432
  const size_t o_s2    = 71303168;   // 4096x1024 f32 = 16777216
  const size_t o_h     = 88080384;   // 2048x7168 bf16 = 29360128 ; later Vcat bf16 [14][1024][2048]
  const size_t o_acat  = 146800640;  // 14x1024x2048 bf16 = 58720256
  const size_t o_smv   = 205520896;
  const size_t o_emv   = o_smv + 16384;
  const size_t o_band  = o_emv + 16384;
  const size_t o_starts= o_band + 524288;
  const size_t o_ends  = o_starts + 8192;
  const size_t o_tk    = o_ends + 8192;
  const size_t o_kv    = o_tk + 8192;
  const size_t o_biasv = o_kv + 256;

  __hip_bfloat16* embsp = (__hip_bfloat16*)(ws + o_embsp);
  __hip_bfloat16* bse   = (__hip_bfloat16*)(ws + o_bse);
  __hip_bfloat16* ssp   = (__hip_bfloat16*)(ws + o_ssp);
  __hip_bfloat16* s2Wsp = (__hip_bfloat16*)(ws + o_s2W);
  __hip_bfloat16* repss = (__hip_bfloat16*)(ws + o_repss);
  __hip_bfloat16* repse = (__hip_bfloat16*)(ws + o_repse);
  __hip_bfloat16* csWb  = (__hip_bfloat16*)(ws + o_csWb);
  __hip_bfloat16* ceWb  = (__hip_bfloat16*)(ws + o_ceWb);
  __hip_bfloat16* Bbig  = (__hip_bfloat16*)(ws + o_Bbig);
  float* se_buf = (float*)(ws + o_se);
  float* s2_buf = (float*)(ws + o_s2);
  __hip_bfloat16* h_buf = (__hip_bfloat16*)(ws + o_h);
  __hip_bfloat16* Vcat  = (__hip_bfloat16*)(ws + o_h);
  __hip_bfloat16* a_cat = (__hip_bfloat16*)(ws + o_acat);
  float* smv_p = (float*)(ws + o_smv);
  float* emv_p = (float*)(ws + o_emv);
  float* band_p = (float*)(ws + o_band);
  int* starts_p = (int*)(ws + o_starts);
  int* ends_p = (int*)(ws + o_ends);
  float* tk_p = (float*)(ws + o_tk);
  int* kv_p = (int*)(ws + o_kv);
  float* biasv_p = (float*)(ws + o_biasv);

  // ---- stage A: se = [emb@smW^T | emb@emW^T] via split3 K-concat (f32-grade) ----
  k_packsplit3<true ><<<4096, 256, 0, stream>>>(x_emb, 1024, x_emb, 4096, embsp);
  k_packsplit3<false><<<2048, 256, 0, stream>>>(smW, 1024, emW, 1024, bse);
  k_gemm97<false, 1><<<dim3(512, 1, 1), 256, 0, stream>>>(embsp, bse, se_buf, smb, embb,
      nullptr, nullptr, 3072, 16, 0, 0, 0, 0, 2048, 4096, 2048);
  k_ln_s<<<4096, 256, 0, stream>>>(se_buf, smg, smbe, msw, msb, smv_p, ssp);
  k_ln_e<<<4096, 256, 0, stream>>>(se_buf, emg, embe, mew, meb, emv_p);

  // ---- stage C: s2 = s@s2eW^T + b ; banded scores ----
  k_packsplit3<false><<<1024, 256, 0, stream>>>(s2eW, 1024, s2eW, 1024, s2Wsp);
  k_gemm97<false, 0><<<dim3(256, 1, 1), 256, 0, stream>>>(ssp, s2Wsp, s2_buf, s2eb, nullptr,
      nullptr, nullptr, 3072, 8, 0, 0, 0, 0, 1024, 4096, 1024);
  k_band<<<512, 512, 0, stream>>>(s2_buf, se_buf, smv_p, emv_p, band_p);

  // ---- stage D: exact top-k ----
  k_topk<<<2, 1024, 0, stream>>>(band_p, masks, starts_p, ends_p, tk_p, kv_p);

  // ---- stage E/F: gather + FC to per-category reps ----
  k_gather<<<2 * NK, 256, 0, stream>>>(x_emb, starts_p, ends_p, repss, repse);
  k_cast4<<<7168, 256, 0, stream>>>(csW, csWb, 1835008);
  k_cast4<<<7168, 256, 0, stream>>>(ceW, ceWb, 1835008);
  k_gemm97<true, 0><<<dim3(896, 1, 1), 256, 0, stream>>>(repss, csWb, h_buf, csb, nullptr,
      nullptr, nullptr, 1024, 56, 0, 0, 0, 0, 7168, 2048, 7168);
  k_gelu_ln_cats<<<2048, 256, 0, stream>>>(h_buf, csg, csbe, a_cat, 0);
  k_gemm97<true, 0><<<dim3(896, 1, 1), 256, 0, stream>>>(repse, ceWb, h_buf, ceb, nullptr,
      nullptr, nullptr, 1024, 56, 0, 0, 0, 0, 7168, 2048, 7168);
  k_packBbig<<<28672, 256, 0, stream>>>(Ws2s, We2e, Ws2e, We2s, Bbig);
  k_gelu_ln_cats<<<2048, 256, 0, stream>>>(h_buf, ceg, cebe, a_cat, 1);

  // ---- stage G: Vcat = a_cat @ Bbig^T (per z, cat = z%7), then logits ----
  k_gemm97<true, 0><<<dim3(128, 1, Z_), 256, 0, stream>>>(a_cat, Bbig, Vcat, nullptr, nullptr,
      nullptr, nullptr, 2048, 16, (long)NK * 2048, (long)2048 * 2048, 1, (long)NK * 2048, 2048, NK, 2048);
  k_bias<<<(Z_ * NK) / 4, 256, 0, stream>>>(a_cat, Bs2s, Be2e, Bs2e, Be2s, biasv_p);
  // logits + fused epilogue (bias[l] + pair + mask) straight into d_out
  k_gemm97<false, 2><<<dim3(64, 1, Z_), 256, 0, stream>>>(a_cat, Vcat, outp, biasv_p, nullptr,
      tk_p, kv_p, 2048, 8, (long)NK * 2048, (long)NK * 2048, 0, (long)MAXK * MAXK, MAXK, MAXK, MAXK);
}

// Round 6
// 747.867 us; speedup vs baseline: 1.1706x; 1.1177x over previous
//
#include <hip/hip_runtime.h>
#include <hip/hip_bf16.h>
#include <math.h>

// ---- problem constants ----
#define S_    2048
#define NC_   7
#define MAXK  819
#define NK    1024          // a_cat/Vcat row stride per z
#define KP    896           // trimmed valid top-k rows (7*128)
#define Z_    14            // B*NUM_CATS
#define NEGV  (-10000.0f)

typedef __attribute__((ext_vector_type(8))) short bf16x8;
typedef __attribute__((ext_vector_type(4))) float f32x4;

#define CFENCE asm volatile("" ::: "memory")
#define BAR    do { CFENCE; __builtin_amdgcn_s_barrier(); CFENCE; } while (0)

__device__ __forceinline__ void gload_lds16(const void* g, void* l) {
  __builtin_amdgcn_global_load_lds((const __attribute__((address_space(1))) unsigned int*)g,
                                   (__attribute__((address_space(3))) unsigned int*)l, 16, 0, 0);
}

__device__ __forceinline__ float gelu_exact(float x) {
  return 0.5f * x * (1.0f + erff(x * 0.70710678118654752f));
}
__device__ __forceinline__ unsigned short f2bf(float x) {
  __hip_bfloat16 h = __float2bfloat16(x);
  return *(unsigned short*)&h;
}
__device__ __forceinline__ float bf2f(unsigned short u) {
  __hip_bfloat16 h; *(unsigned short*)&h = u;
  return __bfloat162float(h);
}

// ============ 256x256 8-wave GEMM, BK=64, 8-phase counted-vmcnt (r3 schedule) ============
// C[m,n] = sum_k A[m,k]*B[n,k]
// EPI 0: optional bias1[n]; EPI 1: bias1/bias2 split at n=1024; EPI 2: logits epilogue
// MERGE: A rows [0,896) -> z, [896,1792) -> z+7 (same for C); B indexed by z (cat).
template<bool OBF16, int EPI, bool MERGE>
__global__ __launch_bounds__(512, 2) void k_gemm8(
    const __hip_bfloat16* __restrict__ A, const __hip_bfloat16* __restrict__ B,
    void* __restrict__ Cv, const float* __restrict__ bias1, const float* __restrict__ bias2,
    const float* __restrict__ tkv, const int* __restrict__ kvp,
    int K, int nbn, long strideA, long strideB, int bmod7, long strideC,
    int ldc, int Mstore, int Nstore)
{
  __shared__ __align__(16) char lds[2][65536];   // per buf: A[0,32K) B[32K,64K)
  const int tid = threadIdx.x;
  const int z = blockIdx.z;
  const int nwg = gridDim.x;
  const int xcd = blockIdx.x & 7, loc = blockIdx.x >> 3;
  const int q = nwg >> 3, r = nwg & 7;
  const int wg = (xcd < r ? xcd * (q + 1) : r * (q + 1) + (xcd - r) * q) + loc;
  const int bm = wg / nbn, bn = wg % nbn;
  const int m0 = bm * 256, n0 = bn * 256;
  const __hip_bfloat16* pA = A + (long)z * strideA;
  const __hip_bfloat16* pB = B + (long)(bmod7 ? (z % 7) : z) * strideB;
  const int wave = tid >> 6, lane = tid & 63;
  const int wm = wave >> 2, wn = wave & 3;
  const int lr = lane & 15, kh = lane >> 4;
  const long Kb = (long)K * 2;

  f32x4 acc[8][4];
  #pragma unroll
  for (int i = 0; i < 8; ++i)
    #pragma unroll
    for (int j = 0; j < 4; ++j)
      #pragma unroll
      for (int rr = 0; rr < 4; ++rr) acc[i][j][rr] = 0.0f;

  // stage one 16KB half-tile (rows rh*128..+127) of K-tile kt into buf bb
  auto stageHalf = [&](int bb, int isB, int rh, int kt) {
    const long kbyte = (long)kt * 128;
    const char* basep;
    if (isB) {
      basep = (const char*)pB + (long)(n0 + rh * 128) * Kb;
    } else if (MERGE) {
      int arow0 = m0 + rh * 128;
      int zb = (arow0 >= KP) ? 1 : 0;
      basep = (const char*)(A + (long)(z + NC_ * zb) * strideA)
              + (long)(arow0 - KP * zb) * Kb;
    } else {
      basep = (const char*)pA + (long)(m0 + rh * 128) * Kb;
    }
    #pragma unroll
    for (int j = 0; j < 2; ++j) {
      int off = j * 8192 + tid * 16;
      int row = off >> 7;                       // 0..127 local
      int col = off & 127;
      int gc = col ^ (((rh * 128 + row) & 7) << 4);
      gload_lds16(basep + (long)row * Kb + kbyte + gc,
                  &lds[bb][isB * 32768 + (rh * 128 + row) * 128 + col]);
    }
  };
  auto readA = [&](int c, int g, int kk) -> bf16x8 {
    int row = wm * 128 + g * 16 + lr;
    int colb = kk * 64 + kh * 16;
    return *(const bf16x8*)&lds[c][row * 128 + (colb ^ ((row & 7) << 4))];
  };
  auto readB = [&](int c, int ni, int kk) -> bf16x8 {
    int row = wn * 64 + ni * 16 + lr;
    int colb = kk * 64 + kh * 16;
    return *(const bf16x8*)&lds[c][32768 + row * 128 + (colb ^ ((row & 7) << 4))];
  };
  auto mfma4 = [&](int g0, bf16x8* af, bf16x8* bfr) {
    __builtin_amdgcn_s_setprio(1);
    #pragma unroll
    for (int mi = 0; mi < 4; ++mi)
      #pragma unroll
      for (int ni = 0; ni < 4; ++ni)
        acc[g0 + mi][ni] = __builtin_amdgcn_mfma_f32_16x16x32_bf16(af[mi], bfr[ni], acc[g0 + mi][ni], 0, 0, 0);
    __builtin_amdgcn_s_setprio(0);
  };

  const int nt = K >> 6;
  // prologue: B0(0) B1(0) A0(0) A1(0) [B0(1)]
  stageHalf(0, 1, 0, 0);
  stageHalf(0, 1, 1, 0);
  stageHalf(0, 0, 0, 0);
  stageHalf(0, 0, 1, 0);
  if (nt > 1) { stageHalf(1, 1, 0, 1); asm volatile("s_waitcnt vmcnt(2)" ::: "memory"); }
  else        { asm volatile("s_waitcnt vmcnt(0)" ::: "memory"); }
  BAR;

  bf16x8 bfr[4], a0f[4], a1f[4];
  for (int t = 0; t < nt; ++t) {
    const int c = t & 1, cn = c ^ 1;
    // ---- phase 0: B kk0 + A g0-3 kk0 ; stage B1(t+1) ----
    #pragma unroll
    for (int i = 0; i < 4; ++i) bfr[i] = readB(c, i, 0);
    #pragma unroll
    for (int i = 0; i < 4; ++i) a0f[i] = readA(c, i, 0);
    if (t + 1 < nt) stageHalf(cn, 1, 1, t + 1);
    BAR;
    mfma4(0, a0f, bfr);
    BAR;
    // ---- phase 1: A g4-7 kk0 ; stage A0(t+1) ----
    #pragma unroll
    for (int i = 0; i < 4; ++i) a1f[i] = readA(c, 4 + i, 0);
    if (t + 1 < nt) stageHalf(cn, 0, 0, t + 1);
    BAR;
    mfma4(4, a1f, bfr);
    BAR;
    // ---- phase 2: B kk1 + A g0-3 kk1 ; stage A1(t+1) ----
    #pragma unroll
    for (int i = 0; i < 4; ++i) bfr[i] = readB(c, i, 1);
    #pragma unroll
    for (int i = 0; i < 4; ++i) a0f[i] = readA(c, i, 1);
    if (t + 1 < nt) stageHalf(cn, 0, 1, t + 1);
    BAR;
    mfma4(0, a0f, bfr);
    BAR;
    // ---- phase 3: A g4-7 kk1 ; stage B0(t+2) ; counted vmcnt ----
    #pragma unroll
    for (int i = 0; i < 4; ++i) a1f[i] = readA(c, 4 + i, 1);
    if (t + 2 < nt) { stageHalf(c, 1, 0, t + 2); asm volatile("s_waitcnt vmcnt(2)" ::: "memory"); }
    else            { asm volatile("s_waitcnt vmcnt(0)" ::: "memory"); }
    BAR;
    mfma4(4, a1f, bfr);
    BAR;
  }

  const long coff = (long)z * strideC;
  int kval = 0, bb_ = 0;
  if (EPI == 2) { bb_ = z / NC_; kval = kvp[bb_]; }
  #pragma unroll
  for (int mi = 0; mi < 8; ++mi) {
    #pragma unroll
    for (int ni = 0; ni < 4; ++ni) {
      int n = n0 + wn * 64 + ni * 16 + lr;
      if (n >= Nstore) continue;
      float badd = 0.f;
      if (EPI == 0) { if (bias1) badd = bias1[n]; }
      if (EPI == 1) badd = (n >= 1024) ? bias2[n - 1024] : bias1[n];
      if (EPI == 2) badd = bias1[z * NK + n] + tkv[bb_ * NK + n];
      #pragma unroll
      for (int rr = 0; rr < 4; ++rr) {
        int m = m0 + wm * 128 + mi * 16 + kh * 4 + rr;
        if (m >= Mstore) continue;
        float v = acc[mi][ni][rr] + badd;
        long co; int mrow;
        if (MERGE) {
          int zb = (m >= KP) ? 1 : 0;
          co = (long)(z + NC_ * zb) * strideC;
          mrow = m - KP * zb;
        } else { co = coff; mrow = m; }
        if (EPI == 2) {
          v += tkv[bb_ * NK + m];
          if (!(n < m && n < kval)) v += NEGV;
        }
        if (OBF16) ((__hip_bfloat16*)Cv)[co + (long)mrow * ldc + n] = __float2bfloat16(v);
        else       ((float*)Cv)[co + (long)mrow * ldc + n] = v;
      }
    }
  }
}

// ============ 128x256 8-wave GEMM, BK=64, triple-buffer depth-2 prefetch ============
// For wide-M shapes needing more blocks (se, s2). EPI 0/1 as above; f32 out.
template<int EPI>
__global__ __launch_bounds__(512, 1) void k_gemm44(
    const __hip_bfloat16* __restrict__ A, const __hip_bfloat16* __restrict__ B,
    float* __restrict__ Cv, const float* __restrict__ bias1, const float* __restrict__ bias2,
    int K, int nbn, int ldc, int Mstore, int Nstore)
{
  __shared__ __align__(16) char lds[3][49152];   // per buf: A[0,16K) B[16K,48K)
  const int tid = threadIdx.x;
  const int nwg = gridDim.x;
  const int xcd = blockIdx.x & 7, loc = blockIdx.x >> 3;
  const int q = nwg >> 3, r = nwg & 7;
  const int wg = (xcd < r ? xcd * (q + 1) : r * (q + 1) + (xcd - r) * q) + loc;
  const int bm = wg / nbn, bn = wg % nbn;
  const int m0 = bm * 128, n0 = bn * 256;
  const int wave = tid >> 6, lane = tid & 63;
  const int wm = wave >> 2, wn = wave & 3;
  const int lr = lane & 15, kh = lane >> 4;
  const long Kb = (long)K * 2;

  f32x4 acc[4][4];
  #pragma unroll
  for (int i = 0; i < 4; ++i)
    #pragma unroll
    for (int j = 0; j < 4; ++j)
      #pragma unroll
      for (int rr = 0; rr < 4; ++rr) acc[i][j][rr] = 0.0f;

  auto stageA = [&](int bb, int kt) {
    const long kbyte = (long)kt * 128;
    const char* basep = (const char*)A + (long)m0 * Kb;
    #pragma unroll
    for (int j = 0; j < 2; ++j) {
      int off = j * 8192 + tid * 16;
      int row = off >> 7, col = off & 127;
      int gc = col ^ ((row & 7) << 4);
      gload_lds16(basep + (long)row * Kb + kbyte + gc, &lds[bb][row * 128 + col]);
    }
  };
  auto stageB = [&](int bb, int kt, int rh) {
    const long kbyte = (long)kt * 128;
    const char* basep = (const char*)B + (long)(n0 + rh * 128) * Kb;
    #pragma unroll
    for (int j = 0; j < 2; ++j) {
      int off = j * 8192 + tid * 16;
      int row = off >> 7, col = off & 127;
      int gc = col ^ (((rh * 128 + row) & 7) << 4);
      gload_lds16(basep + (long)row * Kb + kbyte + gc,
                  &lds[bb][16384 + (rh * 128 + row) * 128 + col]);
    }
  };
  auto readA = [&](int c, int g, int kk) -> bf16x8 {
    int row = wm * 64 + g * 16 + lr;
    int colb = kk * 64 + kh * 16;
    return *(const bf16x8*)&lds[c][row * 128 + (colb ^ ((row & 7) << 4))];
  };
  auto readB = [&](int c, int ni, int kk) -> bf16x8 {
    int row = wn * 64 + ni * 16 + lr;
    int colb = kk * 64 + kh * 16;
    return *(const bf16x8*)&lds[c][16384 + row * 128 + (colb ^ ((row & 7) << 4))];
  };
  auto mfmaAll = [&](bf16x8* af, bf16x8* bfr) {
    __builtin_amdgcn_s_setprio(1);
    #pragma unroll
    for (int mi = 0; mi < 4; ++mi)
      #pragma unroll
      for (int ni = 0; ni < 4; ++ni)
        acc[mi][ni] = __builtin_amdgcn_mfma_f32_16x16x32_bf16(af[mi], bfr[ni], acc[mi][ni], 0, 0, 0);
    __builtin_amdgcn_s_setprio(0);
  };

  const int nt = K >> 6;
  // prologue: stage tile0 -> buf0, tile1 -> buf1
  stageA(0, 0); stageB(0, 0, 0); stageB(0, 0, 1);
  if (nt > 1) { stageA(1, 1); stageB(1, 1, 0); stageB(1, 1, 1);
                asm volatile("s_waitcnt vmcnt(6)" ::: "memory"); }
  else        { asm volatile("s_waitcnt vmcnt(0)" ::: "memory"); }
  BAR;

  bf16x8 af[4], bfr[4];
  int ct = 0;
  for (int t = 0; t < nt; ++t) {
    const int b2 = (ct + 2 >= 3) ? ct - 1 : ct + 2;   // (t+2)%3
    // ---- phase 0: kk0 ; stage A(t+2) ----
    #pragma unroll
    for (int i = 0; i < 4; ++i) bfr[i] = readB(ct, i, 0);
    #pragma unroll
    for (int i = 0; i < 4; ++i) af[i] = readA(ct, i, 0);
    if (t + 2 < nt) stageA(b2, t + 2);
    BAR;
    mfmaAll(af, bfr);
    BAR;
    // ---- phase 1: kk1 ; stage B(t+2) both halves ; counted vmcnt ----
    #pragma unroll
    for (int i = 0; i < 4; ++i) bfr[i] = readB(ct, i, 1);
    #pragma unroll
    for (int i = 0; i < 4; ++i) af[i] = readA(ct, i, 1);
    if (t + 2 < nt) { stageB(b2, t + 2, 0); stageB(b2, t + 2, 1);
                      asm volatile("s_waitcnt vmcnt(6)" ::: "memory"); }
    else            { asm volatile("s_waitcnt vmcnt(0)" ::: "memory"); }
    BAR;
    mfmaAll(af, bfr);
    BAR;
    ct = (ct + 1 >= 3) ? 0 : ct + 1;
  }

  #pragma unroll
  for (int mi = 0; mi < 4; ++mi) {
    #pragma unroll
    for (int ni = 0; ni < 4; ++ni) {
      int n = n0 + wn * 64 + ni * 16 + lr;
      if (n >= Nstore) continue;
      float badd = 0.f;
      if (EPI == 0) { if (bias1) badd = bias1[n]; }
      if (EPI == 1) badd = (n >= 1024) ? bias2[n - 1024] : bias1[n];
      #pragma unroll
      for (int rr = 0; rr < 4; ++rr) {
        int m = m0 + wm * 64 + mi * 16 + kh * 4 + rr;
        if (m >= Mstore) continue;
        Cv[(long)m * ldc + n] = acc[mi][ni][rr] + badd;
      }
    }
  }
}

// ---------- pack split3: dst rows 3072 wide. APAT: [hi|hi|lo]; else [hi|lo|hi] ----------
template<bool APAT>
__global__ __launch_bounds__(256) void k_packsplit3(const float* __restrict__ s1, long stride1,
                                                    const float* __restrict__ s2, int split,
                                                    __hip_bfloat16* __restrict__ dst) {
  long idx4 = ((long)blockIdx.x * 256 + threadIdx.x) * 4;
  int rrow = (int)(idx4 >> 10), c = (int)(idx4 & 1023);
  const float* src = (rrow < split) ? s1 + (long)rrow * stride1 + c
                                    : s2 + (long)(rrow - split) * 1024 + c;
  float4 v = *(const float4*)src;
  float f[4] = {v.x, v.y, v.z, v.w};
  unsigned short h[4], l4[4];
  #pragma unroll
  for (int i = 0; i < 4; ++i) {
    h[i] = f2bf(f[i]);
    l4[i] = f2bf(f[i] - bf2f(h[i]));
  }
  unsigned short* d = (unsigned short*)dst + (long)rrow * 3072;
  ushort4 hv = {h[0], h[1], h[2], h[3]};
  ushort4 lv = {l4[0], l4[1], l4[2], l4[3]};
  *(ushort4*)(d + c)        = hv;
  *(ushort4*)(d + 1024 + c) = APAT ? hv : lv;
  *(ushort4*)(d + 2048 + c) = APAT ? lv : hv;
}

// ---------- f32 -> bf16 vector cast ----------
__global__ __launch_bounds__(256) void k_cast4(const float* __restrict__ x,
                                               __hip_bfloat16* __restrict__ y, long n4) {
  long i = (long)blockIdx.x * 256 + threadIdx.x;
  if (i >= n4) return;
  float4 v = ((const float4*)x)[i];
  ushort4 o = {f2bf(v.x), f2bf(v.y), f2bf(v.z), f2bf(v.w)};
  ((ushort4*)y)[i] = o;
}

// ---------- pack Bbig[cat][n(2048)][k(2048)] from 4 weight tensors ----------
__global__ __launch_bounds__(256) void k_packBbig(const float* __restrict__ Ws2s,
                                                  const float* __restrict__ We2e,
                                                  const float* __restrict__ Ws2e,
                                                  const float* __restrict__ We2s,
                                                  __hip_bfloat16* __restrict__ dst) {
  long idx4 = ((long)blockIdx.x * 256 + threadIdx.x) * 4;
  long rowid = idx4 >> 11;
  int c = (int)(idx4 & 2047);
  int cat = (int)(rowid >> 11);
  int n = (int)(rowid & 2047);
  const float* src;
  if (n < 1024) src = (c < 1024) ? Ws2s + ((long)cat * 1024 + n) * 1024 + c
                                 : Ws2e + ((long)cat * 1024 + n) * 1024 + (c - 1024);
  else          src = (c < 1024) ? We2s + ((long)cat * 1024 + (n - 1024)) * 1024 + c
                                 : We2e + ((long)cat * 1024 + (n - 1024)) * 1024 + (c - 1024);
  float4 v = *(const float4*)src;
  ushort4 o = {f2bf(v.x), f2bf(v.y), f2bf(v.z), f2bf(v.w)};
  *(ushort4*)((unsigned short*)dst + idx4) = o;
}

// ---------- fused GELU+LN+rowdot+split3 for the s-half ----------
__global__ __launch_bounds__(256) void k_ln_s(const float* __restrict__ se,
                                              const float* __restrict__ g,
                                              const float* __restrict__ beta,
                                              const float* __restrict__ wv,
                                              const float* __restrict__ b0,
                                              float* __restrict__ smv,
                                              __hip_bfloat16* __restrict__ ssp) {
  int r = blockIdx.x;
  int c4 = threadIdx.x;
  float4 x = ((const float4*)(se + (long)r * 2048))[c4];
  float v[4] = {gelu_exact(x.x), gelu_exact(x.y), gelu_exact(x.z), gelu_exact(x.w)};
  float s = v[0] + v[1] + v[2] + v[3];
  float s2 = v[0]*v[0] + v[1]*v[1] + v[2]*v[2] + v[3]*v[3];
  __shared__ float red0[4], red1[4];
  for (int off = 32; off; off >>= 1) { s += __shfl_xor(s, off); s2 += __shfl_xor(s2, off); }
  int w = threadIdx.x >> 6;
  if ((threadIdx.x & 63) == 0) { red0[w] = s; red1[w] = s2; }
  __syncthreads();
  s  = red0[0] + red0[1] + red0[2] + red0[3];
  s2 = red1[0] + red1[1] + red1[2] + red1[3];
  float mu  = s / 1024.0f;
  float var = s2 / 1024.0f - mu * mu;
  float inv = 1.0f / sqrtf(var + 1e-5f);
  float4 gg = ((const float4*)g)[c4], bb = ((const float4*)beta)[c4];
  float y[4] = {(v[0]-mu)*inv*gg.x + bb.x, (v[1]-mu)*inv*gg.y + bb.y,
                (v[2]-mu)*inv*gg.z + bb.z, (v[3]-mu)*inv*gg.w + bb.w};
  float4 w4 = ((const float4*)wv)[c4];
  float d = y[0]*w4.x + y[1]*w4.y + y[2]*w4.z + y[3]*w4.w;
  for (int off = 32; off; off >>= 1) d += __shfl_xor(d, off);
  __syncthreads();
  if ((threadIdx.x & 63) == 0) red0[w] = d;
  __syncthreads();
  if (threadIdx.x == 0)
    smv[r] = red0[0] + red0[1] + red0[2] + red0[3] + b0[0];
  unsigned short h[4], l4[4];
  #pragma unroll
  for (int i = 0; i < 4; ++i) { h[i] = f2bf(y[i]); l4[i] = f2bf(y[i] - bf2f(h[i])); }
  ushort4 hv = {h[0], h[1], h[2], h[3]};
  ushort4 lv = {l4[0], l4[1], l4[2], l4[3]};
  unsigned short* dst = (unsigned short*)ssp + (long)r * 3072 + c4 * 4;
  *(ushort4*)dst          = hv;
  *(ushort4*)(dst + 1024) = hv;
  *(ushort4*)(dst + 2048) = lv;
}

// ---------- fused GELU+LN+rowdot for the e-half (in-place f32) ----------
__global__ __launch_bounds__(256) void k_ln_e(float* __restrict__ se,
                                              const float* __restrict__ g,
                                              const float* __restrict__ beta,
                                              const float* __restrict__ wv,
                                              const float* __restrict__ b0,
                                              float* __restrict__ emv) {
  int r = blockIdx.x;
  int c4 = threadIdx.x;
  float4* rowp = (float4*)(se + (long)r * 2048 + 1024);
  float4 x = rowp[c4];
  float v[4] = {gelu_exact(x.x), gelu_exact(x.y), gelu_exact(x.z), gelu_exact(x.w)};
  float s = v[0] + v[1] + v[2] + v[3];
  float s2 = v[0]*v[0] + v[1]*v[1] + v[2]*v[2] + v[3]*v[3];
  __shared__ float red0[4], red1[4];
  for (int off = 32; off; off >>= 1) { s += __shfl_xor(s, off); s2 += __shfl_xor(s2, off); }
  int w = threadIdx.x >> 6;
  if ((threadIdx.x & 63) == 0) { red0[w] = s; red1[w] = s2; }
  __syncthreads();
  s  = red0[0] + red0[1] + red0[2] + red0[3];
  s2 = red1[0] + red1[1] + red1[2] + red1[3];
  float mu  = s / 1024.0f;
  float var = s2 / 1024.0f - mu * mu;
  float inv = 1.0f / sqrtf(var + 1e-5f);
  float4 gg = ((const float4*)g)[c4], bb = ((const float4*)beta)[c4];
  float4 y = {(v[0]-mu)*inv*gg.x + bb.x, (v[1]-mu)*inv*gg.y + bb.y,
              (v[2]-mu)*inv*gg.z + bb.z, (v[3]-mu)*inv*gg.w + bb.w};
  float4 w4 = ((const float4*)wv)[c4];
  float d = y.x*w4.x + y.y*w4.y + y.z*w4.z + y.w*w4.w;
  for (int off = 32; off; off >>= 1) d += __shfl_xor(d, off);
  __syncthreads();
  if ((threadIdx.x & 63) == 0) red0[w] = d;
  __syncthreads();
  if (threadIdx.x == 0)
    emv[r] = red0[0] + red0[1] + red0[2] + red0[3] + b0[0];
  rowp[c4] = y;
}

// ---------- GELU+LN over 7168 (bf16 in), write bf16 into a_cat[z][k][2048] half ----------
__global__ __launch_bounds__(256) void k_gelu_ln_cats(const __hip_bfloat16* __restrict__ h,
                                                      const float* __restrict__ g,
                                                      const float* __restrict__ beta,
                                                      __hip_bfloat16* __restrict__ a_cat, int half) {
  int r = blockIdx.x;                       // 0..2*KP-1
  int b = (r >= KP) ? 1 : 0, k = r - KP * b;
  const ushort4* row = (const ushort4*)((const unsigned short*)h + (long)r * 7168);
  float v[28];
  float s = 0.f, s2 = 0.f;
  #pragma unroll
  for (int j = 0; j < 7; ++j) {
    ushort4 u = row[threadIdx.x + 256 * j];
    #pragma unroll
    for (int e = 0; e < 4; ++e) {
      float x = bf2f(((const unsigned short*)&u)[e]);
      float ge = gelu_exact(x);
      v[j * 4 + e] = ge; s += ge; s2 += ge * ge;
    }
  }
  __shared__ float red0[4], red1[4];
  for (int off = 32; off; off >>= 1) { s += __shfl_xor(s, off); s2 += __shfl_xor(s2, off); }
  int w = threadIdx.x >> 6;
  if ((threadIdx.x & 63) == 0) { red0[w] = s; red1[w] = s2; }
  __syncthreads();
  s  = red0[0] + red0[1] + red0[2] + red0[3];
  s2 = red1[0] + red1[1] + red1[2] + red1[3];
  float mu  = s / 7168.0f;
  float var = s2 / 7168.0f - mu * mu;
  float inv = 1.0f / sqrtf(var + 1e-5f);
  #pragma unroll
  for (int j = 0; j < 7; ++j) {
    int c0 = (threadIdx.x + 256 * j) * 4;
    int n = c0 >> 10, f = c0 & 1023;
    unsigned short o[4];
    #pragma unroll
    for (int e = 0; e < 4; ++e)
      o[e] = f2bf((v[j * 4 + e] - mu) * inv * g[c0 + e] + beta[c0 + e]);
    ushort4 ov = {o[0], o[1], o[2], o[3]};
    *(ushort4*)((unsigned short*)a_cat + ((long)((b * NC_ + n) * NK + k)) * 2048 + half * 1024 + f) = ov;
  }
}

// ---------- banded scores: 8 s-rows per block, e-rows staged via LDS ----------
__global__ __launch_bounds__(512) void k_band(const float* __restrict__ s2m,
                                              const float* __restrict__ se,
                                              const float* __restrict__ smv,
                                              const float* __restrict__ emv,
                                              float* __restrict__ band) {
  __shared__ float ebuf[2][1024];
  int blk = blockIdx.x;
  int b = blk >> 8;
  int s0 = (blk & 255) * 8;
  int w = threadIdx.x >> 6, l = threadIdx.x & 63;
  int s = s0 + w;
  int tid = threadIdx.x;
  float sreg[16];
  const float* sp = s2m + ((long)(b << 11) + s) * 1024;
  #pragma unroll
  for (int qq = 0; qq < 16; ++qq) sreg[qq] = sp[l + 64 * qq];
  float myS = smv[(b << 11) + s];
  if (l < 32) {
    int j = l;
    if (j >= 30 || s + j >= S_)
      band[((long)(b << 11) + s) * 32 + j] = -3.0e38f;
  }
  {
    const float* ep = se + ((long)(b << 11) + s0) * 2048 + 1024;
    ebuf[0][tid * 2]     = ep[tid * 2];
    ebuf[0][tid * 2 + 1] = ep[tid * 2 + 1];
  }
  for (int it = 0; it < 37; ++it) {
    int t = s0 + it;
    __syncthreads();
    if (it + 1 < 37 && s0 + it + 1 < S_) {
      const float* ep = se + ((long)(b << 11) + s0 + it + 1) * 2048 + 1024;
      ebuf[(it + 1) & 1][tid * 2]     = ep[tid * 2];
      ebuf[(it + 1) & 1][tid * 2 + 1] = ep[tid * 2 + 1];
    }
    int j = t - s;
    if (t < S_ && j >= 0 && j < 30) {
      const float* eb = ebuf[it & 1];
      float acc = 0.f;
      #pragma unroll
      for (int qq = 0; qq < 16; ++qq) acc += sreg[qq] * eb[l + 64 * qq];
      for (int off = 32; off; off >>= 1) acc += __shfl_xor(acc, off);
      if (l == 0)
        band[((long)(b << 11) + s) * 32 + j] = acc + myS + emv[(b << 11) + t];
    }
  }
}

// ---------- exact top-k (radix select + bitonic), one block per batch ----------
__device__ __forceinline__ void bitonic1024(unsigned* buf) {
  int tid = threadIdx.x;
  __syncthreads();
  for (int k = 2; k <= 1024; k <<= 1)
    for (int j = k >> 1; j > 0; j >>= 1) {
      int ixj = tid ^ j;
      if (ixj > tid) {
        unsigned a = buf[tid], c = buf[ixj];
        bool up = ((tid & k) == 0);
        if (up ? (a > c) : (a < c)) { buf[tid] = c; buf[ixj] = a; }
      }
      __syncthreads();
    }
}

__global__ __launch_bounds__(1024) void k_topk(const float* __restrict__ band,
                                               const int* __restrict__ masks,
                                               int* __restrict__ starts, int* __restrict__ ends,
                                               float* __restrict__ tk, int* __restrict__ kvalid_out) {
  int b = blockIdx.x;
  const float* bb = band + (long)b * 65536;
  __shared__ unsigned hist[16][256];
  __shared__ int sh_digit, sh_R, sh_msum;
  __shared__ unsigned cntG, cntE;
  __shared__ unsigned listG[832];
  __shared__ unsigned listE[1024];
  __shared__ unsigned buf[1024];
  int tid = threadIdx.x;
  int wv = tid >> 6;

  if (tid == 0) sh_msum = 0;
  __syncthreads();
  int pm = masks[b * S_ + tid] + masks[b * S_ + 1024 + tid];
  atomicAdd(&sh_msum, pm);
  __syncthreads();
  int kv = (int)((float)sh_msum * 0.4f);
  if (kv > MAXK) kv = MAXK;

  unsigned prefix = 0;
  int R = kv;
  if (kv > 0) {
    for (int shift = 24; shift >= 0; shift -= 8) {
      for (int i = tid; i < 4096; i += 1024) ((unsigned*)hist)[i] = 0;
      __syncthreads();
      for (int i = tid; i < 65536; i += 1024) {
        unsigned u = __float_as_uint(bb[i]);
        unsigned key = (u & 0x80000000u) ? ~u : (u | 0x80000000u);
        bool ok = (shift == 24) || ((key >> (shift + 8)) == (prefix >> (shift + 8)));
        if (ok) atomicAdd(&hist[wv][(key >> shift) & 255u], 1u);
      }
      __syncthreads();
      if (tid < 256) {
        unsigned sacc = 0;
        #pragma unroll
        for (int ww = 0; ww < 16; ++ww) sacc += hist[ww][tid];
        hist[0][tid] = sacc;
      }
      __syncthreads();
      if (tid == 0) {
        unsigned cum = 0; int d;
        for (d = 255; d >= 0; --d) {
          unsigned hc = hist[0][d];
          if (cum + hc >= (unsigned)R) break;
          cum += hc;
        }
        if (d < 0) d = 0;
        sh_digit = d; sh_R = R - (int)cum;
      }
      __syncthreads();
      prefix |= ((unsigned)sh_digit) << shift;
      R = sh_R;
      __syncthreads();
    }
  }
  if (tid == 0) { cntG = 0; cntE = 0; }
  __syncthreads();
  if (kv > 0) {
    for (int i = tid; i < 65536; i += 1024) {
      unsigned u = __float_as_uint(bb[i]);
      unsigned key = (u & 0x80000000u) ? ~u : (u | 0x80000000u);
      if (key > prefix) { unsigned p = atomicAdd(&cntG, 1u); if (p < 832) listG[p] = (unsigned)i; }
      else if (key == prefix) { unsigned p = atomicAdd(&cntE, 1u); if (p < 1024) listE[p] = (unsigned)i; }
    }
  }
  __syncthreads();
  int nG = (int)cntG, nE = (int)cntE, need = R;
  buf[tid] = (tid < nE) ? listE[tid] : 0xFFFFFFFFu;
  bitonic1024(buf);
  if (tid < need) listG[nG + tid] = buf[tid];
  __syncthreads();
  unsigned v2 = (tid < (unsigned)kv) ? listG[tid] : 0xFFFFFFFFu;
  __syncthreads();
  buf[tid] = v2;
  bitonic1024(buf);
  {
    int s, t; float val;
    if (tid < kv) {
      unsigned i = buf[tid];
      s = (int)(i >> 5); t = s + (int)(i & 31);
      val = bb[i];
    } else {
      s = S_ - 1; t = S_ - 1;
      val = bb[(S_ - 1) * 32 + 0];
    }
    starts[b * NK + tid] = s;
    ends[b * NK + tid] = t;
    tk[b * NK + tid] = val;
  }
  if (tid == 0) kvalid_out[b] = kv;
}

// ---------- gather span reps to bf16 (KP rows per batch, contiguous 2*KP) ----------
__global__ __launch_bounds__(256) void k_gather(const float* __restrict__ emb,
                                                const int* __restrict__ starts,
                                                const int* __restrict__ ends,
                                                __hip_bfloat16* __restrict__ reps_s,
                                                __hip_bfloat16* __restrict__ reps_e) {
  int r = blockIdx.x;                 // 0..2*KP-1
  int b = (r >= KP) ? 1 : 0, k = r - KP * b;
  long ob = (long)r * 1024;
  const float4* ps = (const float4*)(emb + ((long)b * S_ + starts[b * NK + k]) * 1024);
  const float4* pe = (const float4*)(emb + ((long)b * S_ + ends[b * NK + k]) * 1024);
  unsigned short* ds = (unsigned short*)reps_s + ob;
  unsigned short* de = (unsigned short*)reps_e + ob;
  int c4 = threadIdx.x;
  float4 a = ps[c4], e = pe[c4];
  ushort4 oa = {f2bf(a.x), f2bf(a.y), f2bf(a.z), f2bf(a.w)};
  ushort4 oe = {f2bf(e.x), f2bf(e.y), f2bf(e.z), f2bf(e.w)};
  *(ushort4*)(ds + c4 * 4) = oa;
  *(ushort4*)(de + c4 * 4) = oe;
}

// ---------- antecedent bias vector (reads a_cat, KP rows per z) ----------
__global__ __launch_bounds__(256) void k_bias(const __hip_bfloat16* __restrict__ a_cat,
                                              const float* __restrict__ Bs2s, const float* __restrict__ Be2e,
                                              const float* __restrict__ Bs2e, const float* __restrict__ Be2s,
                                              float* __restrict__ biasv) {
  int w = threadIdx.x >> 6, l = threadIdx.x & 63;
  int rid = blockIdx.x * 4 + w;       // z*KP + lidx
  if (rid >= Z_ * KP) return;
  int z = rid / KP, li = rid - z * KP;
  int cat = z % NC_;
  const unsigned short* ar = (const unsigned short*)a_cat + ((long)z * NK + li) * 2048;
  const float* b1 = Bs2s + cat * 1024;
  const float* b2 = Be2s + cat * 1024;
  const float* b3 = Be2e + cat * 1024;
  const float* b4 = Bs2e + cat * 1024;
  float acc = 0.f;
  for (int qq = 0; qq < 16; ++qq) {
    int c = l + 64 * qq;
    acc += bf2f(ar[c]) * (b1[c] + b2[c]);
    acc += bf2f(ar[1024 + c]) * (b3[c] + b4[c]);
  }
  for (int off = 32; off; off >>= 1) acc += __shfl_xor(acc, off);
  if (l == 0) biasv[z * NK + li] = acc;
}

// =====================================================================
extern "C" void kernel_launch(void* const* d_in, const int* in_sizes, int n_in,
                              void* d_out, int out_size, void* d_ws, size_t ws_size,
                              hipStream_t stream) {
  const float* x_emb = (const float*)d_in[0];
  const int*   masks = (const int*)d_in[1];
  const float* smW  = (const float*)d_in[2];
  const float* smb  = (const float*)d_in[3];
  const float* smg  = (const float*)d_in[4];
  const float* smbe = (const float*)d_in[5];
  const float* emW  = (const float*)d_in[6];
  const float* embb = (const float*)d_in[7];
  const float* emg  = (const float*)d_in[8];
  const float* embe = (const float*)d_in[9];
  const float* msw  = (const float*)d_in[10];
  const float* msb  = (const float*)d_in[11];
  const float* mew  = (const float*)d_in[12];
  const float* meb  = (const float*)d_in[13];
  const float* s2eW = (const float*)d_in[14];
  const float* s2eb = (const float*)d_in[15];
  const float* csW  = (const float*)d_in[16];
  const float* csb  = (const float*)d_in[17];
  const float* csg  = (const float*)d_in[18];
  const float* csbe = (const float*)d_in[19];
  const float* ceW  = (const float*)d_in[20];
  const float* ceb  = (const float*)d_in[21];
  const float* ceg  = (const float*)d_in[22];
  const float* cebe = (const float*)d_in[23];
  const float* Ws2s = (const float*)d_in[24];
  const float* We2e = (const float*)d_in[25];
  const float* Ws2e = (const float*)d_in[26];
  const float* We2s = (const float*)d_in[27];
  const float* Bs2s = (const float*)d_in[28];
  const float* Be2e = (const float*)d_in[29];
  const float* Bs2e = (const float*)d_in[30];
  const float* Be2s = (const float*)d_in[31];
  float* outp = (float*)d_out;
  char* ws = (char*)d_ws;
  (void)in_sizes; (void)n_in; (void)out_size; (void)ws_size;

  // ---- workspace layout (liveness-aliased) ----
  const size_t o_embsp = 0;
  const size_t o_bse   = 25165824;
  const size_t o_ssp   = 0;
  const size_t o_s2W   = 25165824;
  const size_t o_repss = 0;
  const size_t o_repse = 4194304;
  const size_t o_csWb  = 8388608;
  const size_t o_ceWb  = 23068672;
  const size_t o_Bbig  = 0;
  const size_t o_se    = 37748736;   // 4096x2048 f32
  const size_t o_s2    = 71303168;   // 4096x1024 f32
  const size_t o_h     = 88080384;   // 1792x7168 bf16 ; later Vcat bf16 [14][1024][2048]
  const size_t o_acat  = 146800640;  // 14x1024x2048 bf16
  const size_t o_smv   = 205520896;
  const size_t o_emv   = o_smv + 16384;
  const size_t o_band  = o_emv + 16384;
  const size_t o_starts= o_band + 524288;
  const size_t o_ends  = o_starts + 8192;
  const size_t o_tk    = o_ends + 8192;
  const size_t o_kv    = o_tk + 8192;
  const size_t o_biasv = o_kv + 256;

  __hip_bfloat16* embsp = (__hip_bfloat16*)(ws + o_embsp);
  __hip_bfloat16* bse   = (__hip_bfloat16*)(ws + o_bse);
  __hip_bfloat16* ssp   = (__hip_bfloat16*)(ws + o_ssp);
  __hip_bfloat16* s2Wsp = (__hip_bfloat16*)(ws + o_s2W);
  __hip_bfloat16* repss = (__hip_bfloat16*)(ws + o_repss);
  __hip_bfloat16* repse = (__hip_bfloat16*)(ws + o_repse);
  __hip_bfloat16* csWb  = (__hip_bfloat16*)(ws + o_csWb);
  __hip_bfloat16* ceWb  = (__hip_bfloat16*)(ws + o_ceWb);
  __hip_bfloat16* Bbig  = (__hip_bfloat16*)(ws + o_Bbig);
  float* se_buf = (float*)(ws + o_se);
  float* s2_buf = (float*)(ws + o_s2);
  __hip_bfloat16* h_buf = (__hip_bfloat16*)(ws + o_h);
  __hip_bfloat16* Vcat  = (__hip_bfloat16*)(ws + o_h);
  __hip_bfloat16* a_cat = (__hip_bfloat16*)(ws + o_acat);
  float* smv_p = (float*)(ws + o_smv);
  float* emv_p = (float*)(ws + o_emv);
  float* band_p = (float*)(ws + o_band);
  int* starts_p = (int*)(ws + o_starts);
  int* ends_p = (int*)(ws + o_ends);
  float* tk_p = (float*)(ws + o_tk);
  int* kv_p = (int*)(ws + o_kv);
  float* biasv_p = (float*)(ws + o_biasv);

  // ---- stage A: se = [emb@smW^T | emb@emW^T] via split3 K-concat (f32-grade) ----
  k_packsplit3<true ><<<4096, 256, 0, stream>>>(x_emb, 1024, x_emb, 4096, embsp);
  k_packsplit3<false><<<2048, 256, 0, stream>>>(smW, 1024, emW, 1024, bse);
  k_gemm44<1><<<dim3(256, 1, 1), 512, 0, stream>>>(embsp, bse, se_buf, smb, embb,
      3072, 8, 2048, 4096, 2048);
  k_ln_s<<<4096, 256, 0, stream>>>(se_buf, smg, smbe, msw, msb, smv_p, ssp);
  k_ln_e<<<4096, 256, 0, stream>>>(se_buf, emg, embe, mew, meb, emv_p);

  // ---- stage C: s2 = s@s2eW^T + b ; banded scores ----
  k_packsplit3<false><<<1024, 256, 0, stream>>>(s2eW, 1024, s2eW, 1024, s2Wsp);
  k_gemm44<0><<<dim3(128, 1, 1), 512, 0, stream>>>(ssp, s2Wsp, s2_buf, s2eb, nullptr,
      3072, 4, 1024, 4096, 1024);
  k_band<<<512, 512, 0, stream>>>(s2_buf, se_buf, smv_p, emv_p, band_p);

  // ---- stage D: exact top-k ----
  k_topk<<<2, 1024, 0, stream>>>(band_p, masks, starts_p, ends_p, tk_p, kv_p);

  // ---- stage E/F: gather + FC (M = 2*KP = 1792) ----
  k_gather<<<2 * KP, 256, 0, stream>>>(x_emb, starts_p, ends_p, repss, repse);
  k_cast4<<<7168, 256, 0, stream>>>(csW, csWb, 1835008);
  k_cast4<<<7168, 256, 0, stream>>>(ceW, ceWb, 1835008);
  k_gemm8<true, 0, false><<<dim3(196, 1, 1), 512, 0, stream>>>(repss, csWb, h_buf, csb, nullptr,
      nullptr, nullptr, 1024, 28, 0, 0, 0, 0, 7168, 2 * KP, 7168);
  k_gelu_ln_cats<<<2 * KP, 256, 0, stream>>>(h_buf, csg, csbe, a_cat, 0);
  k_gemm8<true, 0, false><<<dim3(196, 1, 1), 512, 0, stream>>>(repse, ceWb, h_buf, ceb, nullptr,
      nullptr, nullptr, 1024, 28, 0, 0, 0, 0, 7168, 2 * KP, 7168);
  k_packBbig<<<28672, 256, 0, stream>>>(Ws2s, We2e, Ws2e, We2s, Bbig);
  k_gelu_ln_cats<<<2 * KP, 256, 0, stream>>>(h_buf, ceg, cebe, a_cat, 1);

  // ---- stage G: Vcat = a_cat @ Bbig^T, b-merged (grid.z = 7 cats, M = 1792) ----
  k_gemm8<true, 0, true><<<dim3(56, 1, NC_), 512, 0, stream>>>(a_cat, Bbig, Vcat, nullptr, nullptr,
      nullptr, nullptr, 2048, 8, (long)NK * 2048, (long)2048 * 2048, 0, (long)NK * 2048, 2048, 2 * KP, 2048);
  k_bias<<<(Z_ * KP) / 4, 256, 0, stream>>>(a_cat, Bs2s, Be2e, Bs2e, Be2s, biasv_p);
  // logits + fused epilogue (bias[l] + pair + mask) straight into d_out
  k_gemm8<false, 2, false><<<dim3(16, 1, Z_), 512, 0, stream>>>(a_cat, Vcat, outp, biasv_p, nullptr,
      tk_p, kv_p, 2048, 4, (long)NK * 2048, (long)NK * 2048, 0, (long)MAXK * MAXK, MAXK, MAXK, MAXK);
}

// Round 7
// 684.093 us; speedup vs baseline: 1.2797x; 1.0932x over previous
//
#include <hip/hip_runtime.h>
#include <hip/hip_bf16.h>
#include <math.h>

// ---- problem constants ----
#define S_    2048
#define NC_   7
#define MAXK  819
#define NK    1024          // a_cat/Vcat row stride per z
#define KP    896           // trimmed valid top-k rows (7*128)
#define Z_    14            // B*NUM_CATS
#define NEGV  (-10000.0f)

typedef __attribute__((ext_vector_type(8))) short bf16x8;
typedef __attribute__((ext_vector_type(4))) float f32x4;

#define CFENCE asm volatile("" ::: "memory")
#define BAR    do { CFENCE; __builtin_amdgcn_s_barrier(); CFENCE; } while (0)

__device__ __forceinline__ void gload_lds16(const void* g, void* l) {
  __builtin_amdgcn_global_load_lds((const __attribute__((address_space(1))) unsigned int*)g,
                                   (__attribute__((address_space(3))) unsigned int*)l, 16, 0, 0);
}

__device__ __forceinline__ float gelu_exact(float x) {
  return 0.5f * x * (1.0f + erff(x * 0.70710678118654752f));
}
__device__ __forceinline__ unsigned short f2bf(float x) {
  __hip_bfloat16 h = __float2bfloat16(x);
  return *(unsigned short*)&h;
}
__device__ __forceinline__ float bf2f(unsigned short u) {
  __hip_bfloat16 h; *(unsigned short*)&h = u;
  return __bfloat162float(h);
}
__device__ __forceinline__ unsigned fkey(float f) {
  unsigned u = __float_as_uint(f);
  return (u & 0x80000000u) ? ~u : (u | 0x80000000u);
}

// ============ 256x256 8-wave GEMM, BK=64, 8-phase counted-vmcnt (r3 schedule) ============
template<bool OBF16, int EPI>
__global__ __launch_bounds__(512, 2) void k_gemm8(
    const __hip_bfloat16* __restrict__ A, const __hip_bfloat16* __restrict__ B,
    void* __restrict__ Cv, const float* __restrict__ bias1, const float* __restrict__ bias2,
    const float* __restrict__ tkv, const int* __restrict__ kvp,
    int K, int nbn, long strideA, long strideB, int bmod7, long strideC,
    int ldc, int Mstore, int Nstore)
{
  __shared__ __align__(16) char lds[2][65536];   // per buf: A[0,32K) B[32K,64K)
  const int tid = threadIdx.x;
  const int z = blockIdx.z;
  const int nwg = gridDim.x;
  const int xcd = blockIdx.x & 7, loc = blockIdx.x >> 3;
  const int q = nwg >> 3, r = nwg & 7;
  const int wg = (xcd < r ? xcd * (q + 1) : r * (q + 1) + (xcd - r) * q) + loc;
  const int bm = wg / nbn, bn = wg % nbn;
  const int m0 = bm * 256, n0 = bn * 256;
  const __hip_bfloat16* pA = A + (long)z * strideA;
  const __hip_bfloat16* pB = B + (long)(bmod7 ? (z % 7) : z) * strideB;
  const int wave = tid >> 6, lane = tid & 63;
  const int wm = wave >> 2, wn = wave & 3;
  const int lr = lane & 15, kh = lane >> 4;
  const long Kb = (long)K * 2;

  f32x4 acc[8][4];
  #pragma unroll
  for (int i = 0; i < 8; ++i)
    #pragma unroll
    for (int j = 0; j < 4; ++j)
      #pragma unroll
      for (int rr = 0; rr < 4; ++rr) acc[i][j][rr] = 0.0f;

  auto stageHalf = [&](int bb, int isB, int rh, int kt) {
    const long kbyte = (long)kt * 128;
    const char* basep = isB ? (const char*)pB + (long)(n0 + rh * 128) * Kb
                            : (const char*)pA + (long)(m0 + rh * 128) * Kb;
    #pragma unroll
    for (int j = 0; j < 2; ++j) {
      int off = j * 8192 + tid * 16;
      int row = off >> 7, col = off & 127;
      int gc = col ^ (((rh * 128 + row) & 7) << 4);
      gload_lds16(basep + (long)row * Kb + kbyte + gc,
                  &lds[bb][isB * 32768 + (rh * 128 + row) * 128 + col]);
    }
  };
  auto readA = [&](int c, int g, int kk) -> bf16x8 {
    int row = wm * 128 + g * 16 + lr;
    int colb = kk * 64 + kh * 16;
    return *(const bf16x8*)&lds[c][row * 128 + (colb ^ ((row & 7) << 4))];
  };
  auto readB = [&](int c, int ni, int kk) -> bf16x8 {
    int row = wn * 64 + ni * 16 + lr;
    int colb = kk * 64 + kh * 16;
    return *(const bf16x8*)&lds[c][32768 + row * 128 + (colb ^ ((row & 7) << 4))];
  };
  auto mfma4 = [&](int g0, bf16x8* af, bf16x8* bfr) {
    __builtin_amdgcn_s_setprio(1);
    #pragma unroll
    for (int mi = 0; mi < 4; ++mi)
      #pragma unroll
      for (int ni = 0; ni < 4; ++ni)
        acc[g0 + mi][ni] = __builtin_amdgcn_mfma_f32_16x16x32_bf16(af[mi], bfr[ni], acc[g0 + mi][ni], 0, 0, 0);
    __builtin_amdgcn_s_setprio(0);
  };

  const int nt = K >> 6;
  stageHalf(0, 1, 0, 0);
  stageHalf(0, 1, 1, 0);
  stageHalf(0, 0, 0, 0);
  stageHalf(0, 0, 1, 0);
  if (nt > 1) { stageHalf(1, 1, 0, 1); asm volatile("s_waitcnt vmcnt(2)" ::: "memory"); }
  else        { asm volatile("s_waitcnt vmcnt(0)" ::: "memory"); }
  BAR;

  bf16x8 bfr[4], a0f[4], a1f[4];
  for (int t = 0; t < nt; ++t) {
    const int c = t & 1, cn = c ^ 1;
    #pragma unroll
    for (int i = 0; i < 4; ++i) bfr[i] = readB(c, i, 0);
    #pragma unroll
    for (int i = 0; i < 4; ++i) a0f[i] = readA(c, i, 0);
    if (t + 1 < nt) stageHalf(cn, 1, 1, t + 1);
    BAR;
    mfma4(0, a0f, bfr);
    BAR;
    #pragma unroll
    for (int i = 0; i < 4; ++i) a1f[i] = readA(c, 4 + i, 0);
    if (t + 1 < nt) stageHalf(cn, 0, 0, t + 1);
    BAR;
    mfma4(4, a1f, bfr);
    BAR;
    #pragma unroll
    for (int i = 0; i < 4; ++i) bfr[i] = readB(c, i, 1);
    #pragma unroll
    for (int i = 0; i < 4; ++i) a0f[i] = readA(c, i, 1);
    if (t + 1 < nt) stageHalf(cn, 0, 1, t + 1);
    BAR;
    mfma4(0, a0f, bfr);
    BAR;
    #pragma unroll
    for (int i = 0; i < 4; ++i) a1f[i] = readA(c, 4 + i, 1);
    if (t + 2 < nt) { stageHalf(c, 1, 0, t + 2); asm volatile("s_waitcnt vmcnt(2)" ::: "memory"); }
    else            { asm volatile("s_waitcnt vmcnt(0)" ::: "memory"); }
    BAR;
    mfma4(4, a1f, bfr);
    BAR;
  }

  const long coff = (long)z * strideC;
  int kval = 0, bb_ = 0;
  if (EPI == 2) { bb_ = z / NC_; kval = kvp[bb_]; }
  #pragma unroll
  for (int mi = 0; mi < 8; ++mi) {
    #pragma unroll
    for (int ni = 0; ni < 4; ++ni) {
      int n = n0 + wn * 64 + ni * 16 + lr;
      if (n >= Nstore) continue;
      float badd = 0.f;
      if (EPI == 0) { if (bias1) badd = bias1[n]; }
      if (EPI == 1) badd = (n >= 1024) ? bias2[n - 1024] : bias1[n];
      if (EPI == 2) badd = bias1[z * NK + n] + tkv[bb_ * NK + n];
      #pragma unroll
      for (int rr = 0; rr < 4; ++rr) {
        int m = m0 + wm * 128 + mi * 16 + kh * 4 + rr;
        if (m >= Mstore) continue;
        float v = acc[mi][ni][rr] + badd;
        if (EPI == 2) {
          v += tkv[bb_ * NK + m];
          if (!(n < m && n < kval)) v += NEGV;
        }
        if (OBF16) ((__hip_bfloat16*)Cv)[coff + (long)m * ldc + n] = __float2bfloat16(v);
        else       ((float*)Cv)[coff + (long)m * ldc + n] = v;
      }
    }
  }
}

// ============ 128xBN 8-wave GEMM, BK=64, triple-buffer depth-2 prefetch ============
template<int EPI, int BN>
__global__ __launch_bounds__(512, 1) void k_gemm44(
    const __hip_bfloat16* __restrict__ A, const __hip_bfloat16* __restrict__ B,
    float* __restrict__ Cv, const float* __restrict__ bias1, const float* __restrict__ bias2,
    int K, int nbn, int ldc, int Mstore, int Nstore)
{
  constexpr int NI = BN / 64;                    // 4 or 2
  constexpr int NBH = BN / 128;                  // B half-tiles: 2 or 1
  __shared__ __align__(16) char lds[3][16384 + BN * 128];
  const int tid = threadIdx.x;
  const int nwg = gridDim.x;
  const int xcd = blockIdx.x & 7, loc = blockIdx.x >> 3;
  const int q = nwg >> 3, r = nwg & 7;
  const int wg = (xcd < r ? xcd * (q + 1) : r * (q + 1) + (xcd - r) * q) + loc;
  const int bm = wg / nbn, bn = wg % nbn;
  const int m0 = bm * 128, n0 = bn * BN;
  const int wave = tid >> 6, lane = tid & 63;
  const int wm = wave >> 2, wn = wave & 3;
  const int lr = lane & 15, kh = lane >> 4;
  const long Kb = (long)K * 2;

  f32x4 acc[4][NI];
  #pragma unroll
  for (int i = 0; i < 4; ++i)
    #pragma unroll
    for (int j = 0; j < NI; ++j)
      #pragma unroll
      for (int rr = 0; rr < 4; ++rr) acc[i][j][rr] = 0.0f;

  auto stageA = [&](int bb, int kt) {
    const long kbyte = (long)kt * 128;
    const char* basep = (const char*)A + (long)m0 * Kb;
    #pragma unroll
    for (int j = 0; j < 2; ++j) {
      int off = j * 8192 + tid * 16;
      int row = off >> 7, col = off & 127;
      int gc = col ^ ((row & 7) << 4);
      gload_lds16(basep + (long)row * Kb + kbyte + gc, &lds[bb][row * 128 + col]);
    }
  };
  auto stageB = [&](int bb, int kt, int rh) {
    const long kbyte = (long)kt * 128;
    const char* basep = (const char*)B + (long)(n0 + rh * 128) * Kb;
    #pragma unroll
    for (int j = 0; j < 2; ++j) {
      int off = j * 8192 + tid * 16;
      int row = off >> 7, col = off & 127;
      int gc = col ^ (((rh * 128 + row) & 7) << 4);
      gload_lds16(basep + (long)row * Kb + kbyte + gc,
                  &lds[bb][16384 + (rh * 128 + row) * 128 + col]);
    }
  };
  auto readA = [&](int c, int g, int kk) -> bf16x8 {
    int row = wm * 64 + g * 16 + lr;
    int colb = kk * 64 + kh * 16;
    return *(const bf16x8*)&lds[c][row * 128 + (colb ^ ((row & 7) << 4))];
  };
  auto readB = [&](int c, int ni, int kk) -> bf16x8 {
    int row = wn * (NI * 16) + ni * 16 + lr;
    int colb = kk * 64 + kh * 16;
    return *(const bf16x8*)&lds[c][16384 + row * 128 + (colb ^ ((row & 7) << 4))];
  };
  auto mfmaAll = [&](bf16x8* af, bf16x8* bfr) {
    __builtin_amdgcn_s_setprio(1);
    #pragma unroll
    for (int mi = 0; mi < 4; ++mi)
      #pragma unroll
      for (int ni = 0; ni < NI; ++ni)
        acc[mi][ni] = __builtin_amdgcn_mfma_f32_16x16x32_bf16(af[mi], bfr[ni], acc[mi][ni], 0, 0, 0);
    __builtin_amdgcn_s_setprio(0);
  };

  const int nt = K >> 6;
  stageA(0, 0);
  #pragma unroll
  for (int rh = 0; rh < NBH; ++rh) stageB(0, 0, rh);
  if (nt > 1) {
    stageA(1, 1);
    #pragma unroll
    for (int rh = 0; rh < NBH; ++rh) stageB(1, 1, rh);
    if (BN == 256) asm volatile("s_waitcnt vmcnt(6)" ::: "memory");
    else           asm volatile("s_waitcnt vmcnt(4)" ::: "memory");
  } else {
    asm volatile("s_waitcnt vmcnt(0)" ::: "memory");
  }
  BAR;

  bf16x8 af[4], bfr[NI];
  int ct = 0;
  for (int t = 0; t < nt; ++t) {
    const int b2 = (ct + 2 >= 3) ? ct - 1 : ct + 2;
    #pragma unroll
    for (int i = 0; i < NI; ++i) bfr[i] = readB(ct, i, 0);
    #pragma unroll
    for (int i = 0; i < 4; ++i) af[i] = readA(ct, i, 0);
    if (t + 2 < nt) stageA(b2, t + 2);
    BAR;
    mfmaAll(af, bfr);
    BAR;
    #pragma unroll
    for (int i = 0; i < NI; ++i) bfr[i] = readB(ct, i, 1);
    #pragma unroll
    for (int i = 0; i < 4; ++i) af[i] = readA(ct, i, 1);
    if (t + 2 < nt) {
      #pragma unroll
      for (int rh = 0; rh < NBH; ++rh) stageB(b2, t + 2, rh);
      if (BN == 256) asm volatile("s_waitcnt vmcnt(6)" ::: "memory");
      else           asm volatile("s_waitcnt vmcnt(4)" ::: "memory");
    } else {
      asm volatile("s_waitcnt vmcnt(0)" ::: "memory");
    }
    BAR;
    mfmaAll(af, bfr);
    BAR;
    ct = (ct + 1 >= 3) ? 0 : ct + 1;
  }

  #pragma unroll
  for (int mi = 0; mi < 4; ++mi) {
    #pragma unroll
    for (int ni = 0; ni < NI; ++ni) {
      int n = n0 + wn * (NI * 16) + ni * 16 + lr;
      if (n >= Nstore) continue;
      float badd = 0.f;
      if (EPI == 0) { if (bias1) badd = bias1[n]; }
      if (EPI == 1) badd = (n >= 1024) ? bias2[n - 1024] : bias1[n];
      #pragma unroll
      for (int rr = 0; rr < 4; ++rr) {
        int m = m0 + wm * 64 + mi * 16 + kh * 4 + rr;
        if (m >= Mstore) continue;
        Cv[(long)m * ldc + n] = acc[mi][ni][rr] + badd;
      }
    }
  }
}

// ---------- pack split3 ----------
template<bool APAT>
__global__ __launch_bounds__(256) void k_packsplit3(const float* __restrict__ s1, long stride1,
                                                    const float* __restrict__ s2, int split,
                                                    __hip_bfloat16* __restrict__ dst) {
  long idx4 = ((long)blockIdx.x * 256 + threadIdx.x) * 4;
  int rrow = (int)(idx4 >> 10), c = (int)(idx4 & 1023);
  const float* src = (rrow < split) ? s1 + (long)rrow * stride1 + c
                                    : s2 + (long)(rrow - split) * 1024 + c;
  float4 v = *(const float4*)src;
  float f[4] = {v.x, v.y, v.z, v.w};
  unsigned short h[4], l4[4];
  #pragma unroll
  for (int i = 0; i < 4; ++i) {
    h[i] = f2bf(f[i]);
    l4[i] = f2bf(f[i] - bf2f(h[i]));
  }
  unsigned short* d = (unsigned short*)dst + (long)rrow * 3072;
  ushort4 hv = {h[0], h[1], h[2], h[3]};
  ushort4 lv = {l4[0], l4[1], l4[2], l4[3]};
  *(ushort4*)(d + c)        = hv;
  *(ushort4*)(d + 1024 + c) = APAT ? hv : lv;
  *(ushort4*)(d + 2048 + c) = APAT ? lv : hv;
}

// ---------- f32 -> bf16 vector cast ----------
__global__ __launch_bounds__(256) void k_cast4(const float* __restrict__ x,
                                               __hip_bfloat16* __restrict__ y, long n4) {
  long i = (long)blockIdx.x * 256 + threadIdx.x;
  if (i >= n4) return;
  float4 v = ((const float4*)x)[i];
  ushort4 o = {f2bf(v.x), f2bf(v.y), f2bf(v.z), f2bf(v.w)};
  ((ushort4*)y)[i] = o;
}

// ---------- pack Bbig[cat][n(2048)][k(2048)] ----------
__global__ __launch_bounds__(256) void k_packBbig(const float* __restrict__ Ws2s,
                                                  const float* __restrict__ We2e,
                                                  const float* __restrict__ Ws2e,
                                                  const float* __restrict__ We2s,
                                                  __hip_bfloat16* __restrict__ dst) {
  long idx4 = ((long)blockIdx.x * 256 + threadIdx.x) * 4;
  long rowid = idx4 >> 11;
  int c = (int)(idx4 & 2047);
  int cat = (int)(rowid >> 11);
  int n = (int)(rowid & 2047);
  const float* src;
  if (n < 1024) src = (c < 1024) ? Ws2s + ((long)cat * 1024 + n) * 1024 + c
                                 : Ws2e + ((long)cat * 1024 + n) * 1024 + (c - 1024);
  else          src = (c < 1024) ? We2s + ((long)cat * 1024 + (n - 1024)) * 1024 + c
                                 : We2e + ((long)cat * 1024 + (n - 1024)) * 1024 + (c - 1024);
  float4 v = *(const float4*)src;
  ushort4 o = {f2bf(v.x), f2bf(v.y), f2bf(v.z), f2bf(v.w)};
  *(ushort4*)((unsigned short*)dst + idx4) = o;
}

// ---------- fused GELU+LN+rowdot for BOTH halves; s-half also split3-packs ----------
__global__ __launch_bounds__(512) void k_ln_se(float* __restrict__ se,
                                               const float* __restrict__ sg, const float* __restrict__ sbe,
                                               const float* __restrict__ eg, const float* __restrict__ ebe,
                                               const float* __restrict__ msw, const float* __restrict__ msb,
                                               const float* __restrict__ mew, const float* __restrict__ meb,
                                               float* __restrict__ smv, float* __restrict__ emv,
                                               __hip_bfloat16* __restrict__ ssp) {
  int r = blockIdx.x;
  int tid = threadIdx.x;
  int half = tid >> 8;                    // 0: s, 1: e
  int c4 = tid & 255;
  int w8 = tid >> 6;
  const float* g    = half ? eg : sg;
  const float* beta = half ? ebe : sbe;
  const float* wv   = half ? mew : msw;
  float4* rowp = (float4*)(se + (long)r * 2048 + half * 1024);
  float4 x = rowp[c4];
  float v[4] = {gelu_exact(x.x), gelu_exact(x.y), gelu_exact(x.z), gelu_exact(x.w)};
  float s = v[0] + v[1] + v[2] + v[3];
  float s2 = v[0]*v[0] + v[1]*v[1] + v[2]*v[2] + v[3]*v[3];
  __shared__ float red0[8], red1[8];
  for (int off = 32; off; off >>= 1) { s += __shfl_xor(s, off); s2 += __shfl_xor(s2, off); }
  if ((tid & 63) == 0) { red0[w8] = s; red1[w8] = s2; }
  __syncthreads();
  s  = red0[half*4] + red0[half*4+1] + red0[half*4+2] + red0[half*4+3];
  s2 = red1[half*4] + red1[half*4+1] + red1[half*4+2] + red1[half*4+3];
  float mu  = s / 1024.0f;
  float var = s2 / 1024.0f - mu * mu;
  float inv = 1.0f / sqrtf(var + 1e-5f);
  float4 gg = ((const float4*)g)[c4], bb = ((const float4*)beta)[c4];
  float y[4] = {(v[0]-mu)*inv*gg.x + bb.x, (v[1]-mu)*inv*gg.y + bb.y,
                (v[2]-mu)*inv*gg.z + bb.z, (v[3]-mu)*inv*gg.w + bb.w};
  float4 w4 = ((const float4*)wv)[c4];
  float d = y[0]*w4.x + y[1]*w4.y + y[2]*w4.z + y[3]*w4.w;
  for (int off = 32; off; off >>= 1) d += __shfl_xor(d, off);
  __syncthreads();
  if ((tid & 63) == 0) red0[w8] = d;
  __syncthreads();
  if ((tid & 255) == 0) {
    float dv = red0[half*4] + red0[half*4+1] + red0[half*4+2] + red0[half*4+3];
    if (half == 0) smv[r] = dv + msb[0];
    else           emv[r] = dv + meb[0];
  }
  if (half == 0) {
    unsigned short h[4], l4[4];
    #pragma unroll
    for (int i = 0; i < 4; ++i) { h[i] = f2bf(y[i]); l4[i] = f2bf(y[i] - bf2f(h[i])); }
    ushort4 hv = {h[0], h[1], h[2], h[3]};
    ushort4 lv = {l4[0], l4[1], l4[2], l4[3]};
    unsigned short* dst = (unsigned short*)ssp + (long)r * 3072 + c4 * 4;
    *(ushort4*)dst          = hv;
    *(ushort4*)(dst + 1024) = hv;
    *(ushort4*)(dst + 2048) = lv;
  } else {
    float4 yo = {y[0], y[1], y[2], y[3]};
    rowp[c4] = yo;     // e-half LN'd in place (used by k_band)
  }
}

// ---------- GELU+LN over 7168 (bf16 in) -> a_cat halves ----------
__global__ __launch_bounds__(256) void k_gelu_ln_cats(const __hip_bfloat16* __restrict__ h,
                                                      const float* __restrict__ g,
                                                      const float* __restrict__ beta,
                                                      __hip_bfloat16* __restrict__ a_cat, int half) {
  int r = blockIdx.x;                       // 0..2*KP-1
  int b = (r >= KP) ? 1 : 0, k = r - KP * b;
  const ushort4* row = (const ushort4*)((const unsigned short*)h + (long)r * 7168);
  float v[28];
  float s = 0.f, s2 = 0.f;
  #pragma unroll
  for (int j = 0; j < 7; ++j) {
    ushort4 u = row[threadIdx.x + 256 * j];
    #pragma unroll
    for (int e = 0; e < 4; ++e) {
      float x = bf2f(((const unsigned short*)&u)[e]);
      float ge = gelu_exact(x);
      v[j * 4 + e] = ge; s += ge; s2 += ge * ge;
    }
  }
  __shared__ float red0[4], red1[4];
  for (int off = 32; off; off >>= 1) { s += __shfl_xor(s, off); s2 += __shfl_xor(s2, off); }
  int w = threadIdx.x >> 6;
  if ((threadIdx.x & 63) == 0) { red0[w] = s; red1[w] = s2; }
  __syncthreads();
  s  = red0[0] + red0[1] + red0[2] + red0[3];
  s2 = red1[0] + red1[1] + red1[2] + red1[3];
  float mu  = s / 7168.0f;
  float var = s2 / 7168.0f - mu * mu;
  float inv = 1.0f / sqrtf(var + 1e-5f);
  #pragma unroll
  for (int j = 0; j < 7; ++j) {
    int c0 = (threadIdx.x + 256 * j) * 4;
    int n = c0 >> 10, f = c0 & 1023;
    unsigned short o[4];
    #pragma unroll
    for (int e = 0; e < 4; ++e)
      o[e] = f2bf((v[j * 4 + e] - mu) * inv * g[c0 + e] + beta[c0 + e]);
    ushort4 ov = {o[0], o[1], o[2], o[3]};
    *(ushort4*)((unsigned short*)a_cat + ((long)((b * NC_ + n) * NK + k)) * 2048 + half * 1024 + f) = ov;
  }
}

// ---------- banded scores ----------
__global__ __launch_bounds__(512) void k_band(const float* __restrict__ s2m,
                                              const float* __restrict__ se,
                                              const float* __restrict__ smv,
                                              const float* __restrict__ emv,
                                              float* __restrict__ band) {
  __shared__ float ebuf[2][1024];
  int blk = blockIdx.x;
  int b = blk >> 8;
  int s0 = (blk & 255) * 8;
  int w = threadIdx.x >> 6, l = threadIdx.x & 63;
  int s = s0 + w;
  int tid = threadIdx.x;
  float sreg[16];
  const float* sp = s2m + ((long)(b << 11) + s) * 1024;
  #pragma unroll
  for (int qq = 0; qq < 16; ++qq) sreg[qq] = sp[l + 64 * qq];
  float myS = smv[(b << 11) + s];
  if (l < 32) {
    int j = l;
    if (j >= 30 || s + j >= S_)
      band[((long)(b << 11) + s) * 32 + j] = -3.0e38f;
  }
  {
    const float* ep = se + ((long)(b << 11) + s0) * 2048 + 1024;
    ebuf[0][tid * 2]     = ep[tid * 2];
    ebuf[0][tid * 2 + 1] = ep[tid * 2 + 1];
  }
  for (int it = 0; it < 37; ++it) {
    int t = s0 + it;
    __syncthreads();
    if (it + 1 < 37 && s0 + it + 1 < S_) {
      const float* ep = se + ((long)(b << 11) + s0 + it + 1) * 2048 + 1024;
      ebuf[(it + 1) & 1][tid * 2]     = ep[tid * 2];
      ebuf[(it + 1) & 1][tid * 2 + 1] = ep[tid * 2 + 1];
    }
    int j = t - s;
    if (t < S_ && j >= 0 && j < 30) {
      const float* eb = ebuf[it & 1];
      float acc = 0.f;
      #pragma unroll
      for (int qq = 0; qq < 16; ++qq) acc += sreg[qq] * eb[l + 64 * qq];
      for (int off = 32; off; off >>= 1) acc += __shfl_xor(acc, off);
      if (l == 0)
        band[((long)(b << 11) + s) * 32 + j] = acc + myS + emv[(b << 11) + t];
    }
  }
}

// ================= parallel exact top-k =================
// zero ghist + counters
__global__ __launch_bounds__(1024) void k_tkzero(unsigned* __restrict__ ghist,
                                                 unsigned* __restrict__ gcnt) {
  int i = blockIdx.x * 1024 + threadIdx.x;
  if (i < 2 * 4096) ghist[i] = 0;
  if (i < 2) gcnt[i] = 0;
}

// per-block LDS 12-bit histograms -> global
__global__ __launch_bounds__(1024) void k_tkhist(const float* __restrict__ band,
                                                 unsigned* __restrict__ ghist) {
  int b = blockIdx.y;
  const float* bb = band + (long)b * 65536;
  __shared__ unsigned lh[4096];
  int tid = threadIdx.x;
  #pragma unroll
  for (int j = 0; j < 4; ++j) lh[tid + j * 1024] = 0;
  __syncthreads();
  int base = blockIdx.x * 4096;
  #pragma unroll
  for (int j = 0; j < 4; ++j) {
    unsigned key = fkey(bb[base + tid + j * 1024]);
    atomicAdd(&lh[key >> 20], 1u);
  }
  __syncthreads();
  #pragma unroll
  for (int j = 0; j < 4; ++j) {
    unsigned v = lh[tid + j * 1024];
    if (v) atomicAdd(&ghist[b * 4096 + tid + j * 1024], v);
  }
}

// suffix-scan to find 12-bit threshold digit + kv (mask sum); sel[b*2]={thr12}, sel[b*2+1]={kv}
__global__ __launch_bounds__(1024) void k_tkscan(const unsigned* __restrict__ ghist,
                                                 const int* __restrict__ masks,
                                                 unsigned* __restrict__ sel) {
  int b = blockIdx.x;
  int tid = threadIdx.x;
  __shared__ unsigned cs[1024];
  __shared__ int red[16];
  __shared__ int sh_kv;
  // kv = 0.4 * mask sum
  int pm = masks[b * S_ + tid] + masks[b * S_ + 1024 + tid];
  for (int off = 32; off; off >>= 1) pm += __shfl_xor(pm, off);
  if ((tid & 63) == 0) red[tid >> 6] = pm;
  __syncthreads();
  if (tid == 0) {
    int msum = 0;
    for (int i = 0; i < 16; ++i) msum += red[i];
    int kv = (int)((float)msum * 0.4f);
    if (kv > MAXK) kv = MAXK;
    sh_kv = kv;
  }
  __syncthreads();
  int kv = sh_kv;
  unsigned hbin[4];
  unsigned ssum = 0;
  #pragma unroll
  for (int j = 0; j < 4; ++j) { hbin[j] = ghist[b * 4096 + tid * 4 + j]; ssum += hbin[j]; }
  cs[tid] = ssum;
  __syncthreads();
  for (int off = 1; off < 1024; off <<= 1) {
    unsigned add = (tid + off < 1024) ? cs[tid + off] : 0u;
    __syncthreads();
    cs[tid] += add;
    __syncthreads();
  }
  unsigned above = cs[tid] - ssum;   // count of keys with key12 strictly above this chunk
  if (kv > 0) {
    unsigned aa = above;
    for (int j = 3; j >= 0; --j) {
      if (aa < (unsigned)kv && aa + hbin[j] >= (unsigned)kv) sel[b * 2] = (unsigned)(tid * 4 + j);
      aa += hbin[j];
    }
  }
  if (tid == 0) {
    sel[b * 2 + 1] = (unsigned)kv;
    if (kv == 0) sel[b * 2] = 0xFFFFFFFFu;
  }
}

// collect candidate indices with key12 >= thr12
__global__ __launch_bounds__(1024) void k_tkcollect(const float* __restrict__ band,
                                                    const unsigned* __restrict__ sel,
                                                    unsigned* __restrict__ cand,
                                                    unsigned* __restrict__ gcnt) {
  int b = blockIdx.y;
  const float* bb = band + (long)b * 65536;
  unsigned thr = sel[b * 2];
  int base = blockIdx.x * 4096;
  int tid = threadIdx.x;
  #pragma unroll
  for (int j = 0; j < 4; ++j) {
    int i = base + tid + j * 1024;
    unsigned key = fkey(bb[i]);
    if ((key >> 20) >= thr) {
      unsigned p = atomicAdd(&gcnt[b], 1u);
      cand[(long)b * 65536 + p] = (unsigned)i;
    }
  }
}

__device__ __forceinline__ void bitonic1024(unsigned* buf) {
  int tid = threadIdx.x;
  __syncthreads();
  for (int k = 2; k <= 1024; k <<= 1)
    for (int j = k >> 1; j > 0; j >>= 1) {
      int ixj = tid ^ j;
      if (ixj > tid) {
        unsigned a = buf[tid], c = buf[ixj];
        bool up = ((tid & k) == 0);
        if (up ? (a > c) : (a < c)) { buf[tid] = c; buf[ixj] = a; }
      }
      __syncthreads();
    }
}

// final exact select over candidates
__global__ __launch_bounds__(1024) void k_tkfinal(const float* __restrict__ band,
                                                  const unsigned* __restrict__ cand,
                                                  const unsigned* __restrict__ gcnt,
                                                  const unsigned* __restrict__ sel,
                                                  int* __restrict__ starts, int* __restrict__ ends,
                                                  float* __restrict__ tk, int* __restrict__ kvalid_out) {
  int b = blockIdx.x;
  const float* bb = band + (long)b * 65536;
  const unsigned* cd = cand + (long)b * 65536;
  int nC = (int)gcnt[b];
  int kv = (int)sel[b * 2 + 1];
  __shared__ unsigned hist[256];
  __shared__ int sh_digit, sh_R;
  __shared__ unsigned cntG, cntE;
  __shared__ unsigned listG[832];
  __shared__ unsigned listE[1024];
  __shared__ unsigned buf[1024];
  int tid = threadIdx.x;

  unsigned prefix = 0;
  int R = kv;
  if (kv > 0) {
    for (int shift = 24; shift >= 0; shift -= 8) {
      if (tid < 256) hist[tid] = 0;
      __syncthreads();
      for (int j = tid; j < nC; j += 1024) {
        unsigned key = fkey(bb[cd[j]]);
        bool ok = (shift == 24) || ((key >> (shift + 8)) == (prefix >> (shift + 8)));
        if (ok) atomicAdd(&hist[(key >> shift) & 255u], 1u);
      }
      __syncthreads();
      if (tid == 0) {
        unsigned cum = 0; int d;
        for (d = 255; d >= 0; --d) {
          unsigned hc = hist[d];
          if (cum + hc >= (unsigned)R) break;
          cum += hc;
        }
        if (d < 0) d = 0;
        sh_digit = d; sh_R = R - (int)cum;
      }
      __syncthreads();
      prefix |= ((unsigned)sh_digit) << shift;
      R = sh_R;
      __syncthreads();
    }
  }
  if (tid == 0) { cntG = 0; cntE = 0; }
  __syncthreads();
  if (kv > 0) {
    for (int j = tid; j < nC; j += 1024) {
      unsigned i = cd[j];
      unsigned key = fkey(bb[i]);
      if (key > prefix) { unsigned p = atomicAdd(&cntG, 1u); if (p < 832) listG[p] = i; }
      else if (key == prefix) { unsigned p = atomicAdd(&cntE, 1u); if (p < 1024) listE[p] = i; }
    }
  }
  __syncthreads();
  int nG = (int)cntG, nE = (int)cntE, need = R;
  buf[tid] = (tid < nE) ? listE[tid] : 0xFFFFFFFFu;
  bitonic1024(buf);
  if (tid < need) listG[nG + tid] = buf[tid];
  __syncthreads();
  unsigned v2 = (tid < (unsigned)kv) ? listG[tid] : 0xFFFFFFFFu;
  __syncthreads();
  buf[tid] = v2;
  bitonic1024(buf);
  {
    int s, t; float val;
    if (tid < kv) {
      unsigned i = buf[tid];
      s = (int)(i >> 5); t = s + (int)(i & 31);
      val = bb[i];
    } else {
      s = S_ - 1; t = S_ - 1;
      val = bb[(S_ - 1) * 32 + 0];
    }
    starts[b * NK + tid] = s;
    ends[b * NK + tid] = t;
    tk[b * NK + tid] = val;
  }
  if (tid == 0) kvalid_out[b] = kv;
}

// ---------- gather span reps to bf16 ----------
__global__ __launch_bounds__(256) void k_gather(const float* __restrict__ emb,
                                                const int* __restrict__ starts,
                                                const int* __restrict__ ends,
                                                __hip_bfloat16* __restrict__ reps_s,
                                                __hip_bfloat16* __restrict__ reps_e) {
  int r = blockIdx.x;                 // 0..2*KP-1
  int b = (r >= KP) ? 1 : 0, k = r - KP * b;
  long ob = (long)r * 1024;
  const float4* ps = (const float4*)(emb + ((long)b * S_ + starts[b * NK + k]) * 1024);
  const float4* pe = (const float4*)(emb + ((long)b * S_ + ends[b * NK + k]) * 1024);
  unsigned short* ds = (unsigned short*)reps_s + ob;
  unsigned short* de = (unsigned short*)reps_e + ob;
  int c4 = threadIdx.x;
  float4 a = ps[c4], e = pe[c4];
  ushort4 oa = {f2bf(a.x), f2bf(a.y), f2bf(a.z), f2bf(a.w)};
  ushort4 oe = {f2bf(e.x), f2bf(e.y), f2bf(e.z), f2bf(e.w)};
  *(ushort4*)(ds + c4 * 4) = oa;
  *(ushort4*)(de + c4 * 4) = oe;
}

// ---------- antecedent bias vector ----------
__global__ __launch_bounds__(256) void k_bias(const __hip_bfloat16* __restrict__ a_cat,
                                              const float* __restrict__ Bs2s, const float* __restrict__ Be2e,
                                              const float* __restrict__ Bs2e, const float* __restrict__ Be2s,
                                              float* __restrict__ biasv) {
  int w = threadIdx.x >> 6, l = threadIdx.x & 63;
  int rid = blockIdx.x * 4 + w;
  if (rid >= Z_ * KP) return;
  int z = rid / KP, li = rid - z * KP;
  int cat = z % NC_;
  const unsigned short* ar = (const unsigned short*)a_cat + ((long)z * NK + li) * 2048;
  const float* b1 = Bs2s + cat * 1024;
  const float* b2 = Be2s + cat * 1024;
  const float* b3 = Be2e + cat * 1024;
  const float* b4 = Bs2e + cat * 1024;
  float acc = 0.f;
  for (int qq = 0; qq < 16; ++qq) {
    int c = l + 64 * qq;
    acc += bf2f(ar[c]) * (b1[c] + b2[c]);
    acc += bf2f(ar[1024 + c]) * (b3[c] + b4[c]);
  }
  for (int off = 32; off; off >>= 1) acc += __shfl_xor(acc, off);
  if (l == 0) biasv[z * NK + li] = acc;
}

// =====================================================================
extern "C" void kernel_launch(void* const* d_in, const int* in_sizes, int n_in,
                              void* d_out, int out_size, void* d_ws, size_t ws_size,
                              hipStream_t stream) {
  const float* x_emb = (const float*)d_in[0];
  const int*   masks = (const int*)d_in[1];
  const float* smW  = (const float*)d_in[2];
  const float* smb  = (const float*)d_in[3];
  const float* smg  = (const float*)d_in[4];
  const float* smbe = (const float*)d_in[5];
  const float* emW  = (const float*)d_in[6];
  const float* embb = (const float*)d_in[7];
  const float* emg  = (const float*)d_in[8];
  const float* embe = (const float*)d_in[9];
  const float* msw  = (const float*)d_in[10];
  const float* msb  = (const float*)d_in[11];
  const float* mew  = (const float*)d_in[12];
  const float* meb  = (const float*)d_in[13];
  const float* s2eW = (const float*)d_in[14];
  const float* s2eb = (const float*)d_in[15];
  const float* csW  = (const float*)d_in[16];
  const float* csb  = (const float*)d_in[17];
  const float* csg  = (const float*)d_in[18];
  const float* csbe = (const float*)d_in[19];
  const float* ceW  = (const float*)d_in[20];
  const float* ceb  = (const float*)d_in[21];
  const float* ceg  = (const float*)d_in[22];
  const float* cebe = (const float*)d_in[23];
  const float* Ws2s = (const float*)d_in[24];
  const float* We2e = (const float*)d_in[25];
  const float* Ws2e = (const float*)d_in[26];
  const float* We2s = (const float*)d_in[27];
  const float* Bs2s = (const float*)d_in[28];
  const float* Be2e = (const float*)d_in[29];
  const float* Bs2e = (const float*)d_in[30];
  const float* Be2s = (const float*)d_in[31];
  float* outp = (float*)d_out;
  char* ws = (char*)d_ws;
  (void)in_sizes; (void)n_in; (void)out_size; (void)ws_size;

  // ---- workspace layout ----
  const size_t o_embsp = 0;
  const size_t o_bse   = 25165824;
  const size_t o_ssp   = 0;
  const size_t o_s2W   = 25165824;
  const size_t o_repss = 0;
  const size_t o_repse = 4194304;
  const size_t o_csWb  = 8388608;
  const size_t o_ceWb  = 23068672;
  const size_t o_Bbig  = 0;
  const size_t o_se    = 37748736;
  const size_t o_s2    = 71303168;
  const size_t o_h     = 88080384;
  const size_t o_acat  = 146800640;
  const size_t o_smv   = 205520896;
  const size_t o_emv   = o_smv + 16384;
  const size_t o_band  = o_emv + 16384;
  const size_t o_starts= o_band + 524288;
  const size_t o_ends  = o_starts + 8192;
  const size_t o_tk    = o_ends + 8192;
  const size_t o_kv    = o_tk + 8192;
  const size_t o_biasv = o_kv + 256;
  const size_t o_ghist = o_biasv + 61440;
  const size_t o_sel   = o_ghist + 32768;
  const size_t o_gcnt  = o_sel + 256;
  const size_t o_cand  = o_gcnt + 256;    // 2*65536*4 = 524288

  __hip_bfloat16* embsp = (__hip_bfloat16*)(ws + o_embsp);
  __hip_bfloat16* bse   = (__hip_bfloat16*)(ws + o_bse);
  __hip_bfloat16* ssp   = (__hip_bfloat16*)(ws + o_ssp);
  __hip_bfloat16* s2Wsp = (__hip_bfloat16*)(ws + o_s2W);
  __hip_bfloat16* repss = (__hip_bfloat16*)(ws + o_repss);
  __hip_bfloat16* repse = (__hip_bfloat16*)(ws + o_repse);
  __hip_bfloat16* csWb  = (__hip_bfloat16*)(ws + o_csWb);
  __hip_bfloat16* ceWb  = (__hip_bfloat16*)(ws + o_ceWb);
  __hip_bfloat16* Bbig  = (__hip_bfloat16*)(ws + o_Bbig);
  float* se_buf = (float*)(ws + o_se);
  float* s2_buf = (float*)(ws + o_s2);
  __hip_bfloat16* h_buf = (__hip_bfloat16*)(ws + o_h);
  __hip_bfloat16* Vcat  = (__hip_bfloat16*)(ws + o_h);
  __hip_bfloat16* a_cat = (__hip_bfloat16*)(ws + o_acat);
  float* smv_p = (float*)(ws + o_smv);
  float* emv_p = (float*)(ws + o_emv);
  float* band_p = (float*)(ws + o_band);
  int* starts_p = (int*)(ws + o_starts);
  int* ends_p = (int*)(ws + o_ends);
  float* tk_p = (float*)(ws + o_tk);
  int* kv_p = (int*)(ws + o_kv);
  float* biasv_p = (float*)(ws + o_biasv);
  unsigned* ghist_p = (unsigned*)(ws + o_ghist);
  unsigned* sel_p = (unsigned*)(ws + o_sel);
  unsigned* gcnt_p = (unsigned*)(ws + o_gcnt);
  unsigned* cand_p = (unsigned*)(ws + o_cand);

  // ---- stage A: se = [emb@smW^T | emb@emW^T] ----
  k_packsplit3<true ><<<4096, 256, 0, stream>>>(x_emb, 1024, x_emb, 4096, embsp);
  k_packsplit3<false><<<2048, 256, 0, stream>>>(smW, 1024, emW, 1024, bse);
  k_gemm44<1, 256><<<dim3(256, 1, 1), 512, 0, stream>>>(embsp, bse, se_buf, smb, embb,
      3072, 8, 2048, 4096, 2048);
  k_ln_se<<<4096, 512, 0, stream>>>(se_buf, smg, smbe, emg, embe, msw, msb, mew, meb,
                                    smv_p, emv_p, ssp);

  // ---- stage C: s2 ; banded scores ----
  k_packsplit3<false><<<1024, 256, 0, stream>>>(s2eW, 1024, s2eW, 1024, s2Wsp);
  k_gemm44<0, 128><<<dim3(256, 1, 1), 512, 0, stream>>>(ssp, s2Wsp, s2_buf, s2eb, nullptr,
      3072, 8, 1024, 4096, 1024);
  k_band<<<512, 512, 0, stream>>>(s2_buf, se_buf, smv_p, emv_p, band_p);

  // ---- stage D: parallel exact top-k ----
  k_tkzero<<<9, 1024, 0, stream>>>(ghist_p, gcnt_p);
  k_tkhist<<<dim3(16, 2), 1024, 0, stream>>>(band_p, ghist_p);
  k_tkscan<<<2, 1024, 0, stream>>>(ghist_p, masks, sel_p);
  k_tkcollect<<<dim3(16, 2), 1024, 0, stream>>>(band_p, sel_p, cand_p, gcnt_p);
  k_tkfinal<<<2, 1024, 0, stream>>>(band_p, cand_p, gcnt_p, sel_p,
                                    starts_p, ends_p, tk_p, kv_p);

  // ---- stage E/F: gather + FC (M = 1792) ----
  k_gather<<<2 * KP, 256, 0, stream>>>(x_emb, starts_p, ends_p, repss, repse);
  k_cast4<<<7168, 256, 0, stream>>>(csW, csWb, 1835008);
  k_cast4<<<7168, 256, 0, stream>>>(ceW, ceWb, 1835008);
  k_gemm8<true, 0><<<dim3(196, 1, 1), 512, 0, stream>>>(repss, csWb, h_buf, csb, nullptr,
      nullptr, nullptr, 1024, 28, 0, 0, 0, 0, 7168, 2 * KP, 7168);
  k_gelu_ln_cats<<<2 * KP, 256, 0, stream>>>(h_buf, csg, csbe, a_cat, 0);
  k_gemm8<true, 0><<<dim3(196, 1, 1), 512, 0, stream>>>(repse, ceWb, h_buf, ceb, nullptr,
      nullptr, nullptr, 1024, 28, 0, 0, 0, 0, 7168, 2 * KP, 7168);
  k_packBbig<<<28672, 256, 0, stream>>>(Ws2s, We2e, Ws2e, We2s, Bbig);
  k_gelu_ln_cats<<<2 * KP, 256, 0, stream>>>(h_buf, ceg, cebe, a_cat, 1);

  // ---- stage G: Vcat (r3 unmerged config), bias, logits ----
  k_gemm8<true, 0><<<dim3(32, 1, Z_), 512, 0, stream>>>(a_cat, Bbig, Vcat, nullptr, nullptr,
      nullptr, nullptr, 2048, 8, (long)NK * 2048, (long)2048 * 2048, 1, (long)NK * 2048, 2048, NK, 2048);
  k_bias<<<(Z_ * KP) / 4, 256, 0, stream>>>(a_cat, Bs2s, Be2e, Bs2e, Be2s, biasv_p);
  k_gemm8<false, 2><<<dim3(16, 1, Z_), 512, 0, stream>>>(a_cat, Vcat, outp, biasv_p, nullptr,
      tk_p, kv_p, 2048, 4, (long)NK * 2048, (long)NK * 2048, 0, (long)MAXK * MAXK, MAXK, MAXK, MAXK);
}